// Round 15
// baseline (289.997 us; speedup 1.0000x reference)
//
#include <hip/hip_runtime.h>
#include <hip/hip_bf16.h>

#define NN 50000
#define EE 1600000
#define NEDGE (EE + NN)   // with self loops
#define HH 4
#define HC 128
#define GG 64
#define GMT 64            // nodes per gemm block
#define NBKT 196          // dst buckets of 256 nodes
#define BCAP 12544        // pairs capacity per bucket (mean 8163, +48 sigma)
#define BKE 2048          // edges per bucketize block
#define NB1 ((EE + BKE - 1) / BKE)
#define APH 3125          // aggregate blocks per head pass (16 nodes/block)

__device__ __forceinline__ float lrelu(float x) { return fmaxf(x, 0.2f * x); }

// round-to-nearest-even f32 -> bf16 (as u16), pack two into a uint
__device__ __forceinline__ unsigned packbf2(float a, float b) {
    unsigned ua = __float_as_uint(a);
    ua = (ua + 0x7fffu + ((ua >> 16) & 1u)) >> 16;
    unsigned ub = __float_as_uint(b);
    ub = (ub + 0x7fffu + ((ub >> 16) & 1u)) >> 16;
    return ua | (ub << 16);
}

// ---------------- CSR build: bucketize -> bscan -> debucket ----------------
__global__ __launch_bounds__(256) void binit(int* __restrict__ bcur) {
    int t = blockIdx.x * 256 + threadIdx.x;
    if (t < NBKT) bcur[t] = t * BCAP;
}

// stage (d,s) pairs in LDS grouped by bucket, flush coalesced.
// rank trick: pass-1 atomicAdd returns each edge's rank -> no 2nd atomic pass.
__global__ __launch_bounds__(256) void bucketize(const int* __restrict__ ei,
                                                 int* __restrict__ bcur,
                                                 uint2* __restrict__ pairs) {
    __shared__ int cnt[NBKT], off[NBKT], gbase[NBKT];
    __shared__ int wsum[4], woff[4];
    __shared__ uint2 stage[BKE];
    int t = threadIdx.x;
    int e0 = blockIdx.x * BKE;
    int n = EE - e0; if (n > BKE) n = BKE;
    for (int i = t; i < NBKT; i += 256) cnt[i] = 0;
    __syncthreads();
    unsigned dv[8], sv[8];
    int rk[8];
#pragma unroll
    for (int k = 0; k < 8; ++k) {
        int i = t + k * 256;
        if (i < n) {
            dv[k] = (unsigned)ei[EE + e0 + i];
            sv[k] = (unsigned)ei[e0 + i];
            rk[k] = atomicAdd(&cnt[dv[k] >> 8], 1);
        }
    }
    __syncthreads();
    // exclusive scan of cnt -> off
    {
        int v = (t < NBKT) ? cnt[t] : 0;
        int lane = t & 63, wv = t >> 6;
        int x = v;
#pragma unroll
        for (int o = 1; o < 64; o <<= 1) { int y = __shfl_up(x, o); if (lane >= o) x += y; }
        if (lane == 63) wsum[wv] = x;
        __syncthreads();
        if (t == 0) { int r = 0; for (int k2 = 0; k2 < 4; ++k2) { woff[k2] = r; r += wsum[k2]; } }
        __syncthreads();
        if (t < NBKT) off[t] = x - v + woff[wv];
    }
    __syncthreads();
#pragma unroll
    for (int k = 0; k < 8; ++k) {
        int i = t + k * 256;
        if (i < n) stage[off[dv[k] >> 8] + rk[k]] = make_uint2(dv[k], sv[k]);
    }
    __syncthreads();
    if (t < NBKT) { int c = cnt[t]; gbase[t] = c ? atomicAdd(&bcur[t], c) : 0; }
    __syncthreads();
    // coalesced flush: consecutive i within a bucket -> consecutive global
    for (int i = t; i < n; i += 256) {
        uint2 pr = stage[i];
        int b = (int)(pr.x >> 8);
        pairs[(size_t)gbase[b] + (i - off[b])] = pr;
    }
}

// exclusive scan of per-bucket totals (pairs + self loops) -> bucket bases
__global__ __launch_bounds__(256) void bscan(const int* __restrict__ bcur,
                                             int* __restrict__ bbase) {
    int t = threadIdx.x;
    int v = 0;
    if (t < NBKT) {
        int pcnt = bcur[t] - t * BCAP;
        int nodes = NN - t * 256; if (nodes > 256) nodes = 256;
        v = pcnt + nodes;
    }
    int lane = t & 63, wv = t >> 6;
    int x = v;
#pragma unroll
    for (int o = 1; o < 64; o <<= 1) { int y = __shfl_up(x, o); if (lane >= o) x += y; }
    __shared__ int wsum[4], woff[4];
    if (lane == 63) wsum[wv] = x;
    __syncthreads();
    if (t == 0) { int r = 0; for (int k = 0; k < 4; ++k) { woff[k] = r; r += wsum[k]; } }
    __syncthreads();
    if (t < NBKT) bbase[t] = x - v + woff[wv];
}

// per bucket: derive per-node offsets from the bucket's own pairs,
// write row_start AND node-exact esrc segment (built in LDS, flushed contiguous)
__global__ __launch_bounds__(512) void debucket(const uint2* __restrict__ pairs,
                                                const int* __restrict__ bcur,
                                                const int* __restrict__ bbase,
                                                int* __restrict__ row_start,
                                                int* __restrict__ esrc) {
    __shared__ int cnt[256], off[256], cur[256];
    __shared__ int wsum[4], woff[4];
    __shared__ int stage[BCAP + 256];
    int b = blockIdx.x, t = threadIdx.x;
    int n0 = b * 256;
    int nnode = NN - n0; if (nnode > 256) nnode = 256;
    int pcnt = bcur[b] - b * BCAP;
    int base = bbase[b];
    if (t < 256) cnt[t] = 0;
    __syncthreads();
    // phase 1: per-node counts
    for (int i = t; i < pcnt; i += 512)
        atomicAdd(&cnt[pairs[(size_t)b * BCAP + i].x & 255u], 1);
    __syncthreads();
    // phase 2: exclusive scan of (cnt[j] + self-loop)
    {
        int v = 0, x = 0;
        int lane = t & 63, wv = t >> 6;
        if (t < 256) {
            v = cnt[t] + (t < nnode ? 1 : 0);
            x = v;
#pragma unroll
            for (int o = 1; o < 64; o <<= 1) { int y = __shfl_up(x, o); if (lane >= o) x += y; }
            if (lane == 63) wsum[wv] = x;
        }
        __syncthreads();
        if (t == 0) { int r = 0; for (int k = 0; k < 4; ++k) { woff[k] = r; r += wsum[k]; } }
        __syncthreads();
        if (t < 256) off[t] = x - v + woff[wv];
    }
    __syncthreads();
    // phase 3: self loop first, then pairs
    if (t < nnode) {
        int o = off[t];
        stage[o] = n0 + t;
        cur[t] = o + 1;
        row_start[n0 + t] = base + o;
    }
    __syncthreads();
    for (int i = t; i < pcnt; i += 512) {
        uint2 pr = pairs[(size_t)b * BCAP + i];
        int p = atomicAdd(&cur[pr.x & 255u], 1);
        stage[p] = (int)pr.y;
    }
    __syncthreads();
    // phase 4: contiguous flush
    int tot = pcnt + nnode;
    for (int i = t; i < tot; i += 512) esrc[base + i] = stage[i];
    if (b == NBKT - 1 && t == 0) row_start[NN] = NEDGE;
}

// ---------------- GEMM (X @ W) + per-head alpha dots ----------------
// outputs HEAD-MAJOR: xwb[h][n][32 cols] bf16-packed; as_/ad_[h][n]
__global__ __launch_bounds__(256) void gemm_alpha(
    const float* __restrict__ X, const float* __restrict__ W,
    const float* __restrict__ a_src, const float* __restrict__ a_dst,
    unsigned* __restrict__ xwb, float* __restrict__ as_, float* __restrict__ ad_) {
    __shared__ float xs[GMT][HC + 4];
    int tid = threadIdx.x;
    int n0 = blockIdx.x * GMT;
    for (int i = tid; i < GMT * (HC / 4); i += 256) {
        int r = i >> 5, c4 = i & 31;
        int n = n0 + r;
        float4 v = (n < NN) ? ((const float4*)X)[(size_t)n * 32 + c4]
                            : make_float4(0.f, 0.f, 0.f, 0.f);
        *(float4*)&xs[r][c4 * 4] = v;
    }
    __syncthreads();

    int jg = tid & 31;
    int ng = tid >> 5;
    int h = jg >> 3;          // head of cols jg*4..jg*4+3
    float4 acc[8] = {};
    for (int k = 0; k < HC; k += 4) {
        float4 wr[4];
#pragma unroll
        for (int dk = 0; dk < 4; ++dk) wr[dk] = ((const float4*)W)[(k + dk) * 32 + jg];
#pragma unroll
        for (int r = 0; r < 8; ++r) {
            float4 xv = *(const float4*)&xs[ng * 8 + r][k];
            acc[r].x = fmaf(xv.x, wr[0].x, acc[r].x);
            acc[r].y = fmaf(xv.x, wr[0].y, acc[r].y);
            acc[r].z = fmaf(xv.x, wr[0].z, acc[r].z);
            acc[r].w = fmaf(xv.x, wr[0].w, acc[r].w);
            acc[r].x = fmaf(xv.y, wr[1].x, acc[r].x);
            acc[r].y = fmaf(xv.y, wr[1].y, acc[r].y);
            acc[r].z = fmaf(xv.y, wr[1].z, acc[r].z);
            acc[r].w = fmaf(xv.y, wr[1].w, acc[r].w);
            acc[r].x = fmaf(xv.z, wr[2].x, acc[r].x);
            acc[r].y = fmaf(xv.z, wr[2].y, acc[r].y);
            acc[r].z = fmaf(xv.z, wr[2].z, acc[r].z);
            acc[r].w = fmaf(xv.z, wr[2].w, acc[r].w);
            acc[r].x = fmaf(xv.w, wr[3].x, acc[r].x);
            acc[r].y = fmaf(xv.w, wr[3].y, acc[r].y);
            acc[r].z = fmaf(xv.w, wr[3].z, acc[r].z);
            acc[r].w = fmaf(xv.w, wr[3].w, acc[r].w);
        }
    }
    float4 asv = ((const float4*)a_src)[jg];
    float4 adv = ((const float4*)a_dst)[jg];
#pragma unroll
    for (int r = 0; r < 8; ++r) {
        int n = n0 + ng * 8 + r;
        float ps = acc[r].x * asv.x + acc[r].y * asv.y + acc[r].z * asv.z + acc[r].w * asv.w;
        float pd = acc[r].x * adv.x + acc[r].y * adv.y + acc[r].z * adv.z + acc[r].w * adv.w;
        ps += __shfl_xor(ps, 1); pd += __shfl_xor(pd, 1);
        ps += __shfl_xor(ps, 2); pd += __shfl_xor(pd, 2);
        ps += __shfl_xor(ps, 4); pd += __shfl_xor(pd, 4);
        if (n < NN) {
            // head-major row of 8 uint2 per (h,n)
            ((uint2*)xwb)[((size_t)h * NN + n) * 8 + (jg & 7)] =
                make_uint2(packbf2(acc[r].x, acc[r].y), packbf2(acc[r].z, acc[r].w));
            if ((jg & 7) == 0) {
                as_[(size_t)h * NN + n] = ps;
                ad_[(size_t)h * NN + n] = pd;
            }
        }
    }
}

// ---------------- fused segment softmax + aggregate + bias + ELU ----------------
// Head-pass v2: bid = h*APH + nb. Each wave handles 4 NODES for ONE head
// (16 lanes/node, 4 edges in flight/node, 64 B rows). Concurrent blocks
// share one 3.2 MB table slice -> fits each XCD's 4 MB L2. Same wave count
// and same bytes/iteration as the node-major version.
__global__ __launch_bounds__(256) void aggregate(
    const int* __restrict__ esrc, const int* __restrict__ row_start,
    const float* __restrict__ as_, const float* __restrict__ ad_,
    const unsigned* __restrict__ xwb, const float* __restrict__ bias,
    float* __restrict__ out) {
    __shared__ float2 sw_all[4][4][17];
    int bid = blockIdx.x;
    int hh = bid / APH;
    int nb = bid - hh * APH;
    int wid = (int)(threadIdx.x >> 6);
    int lane = threadIdx.x & 63;
    int g = lane >> 4;               // node slot in wave (0..3)
    int u = lane & 15;               // lane within node group
    int node = nb * 16 + wid * 4 + g;   // APH*16 == NN, always valid
    float2 (*sw)[17] = sw_all[wid];
    int beg = row_start[node];
    int end = row_start[node + 1];
    const float* ash = as_ + (size_t)hh * NN;
    float adh = ad_[(size_t)hh * NN + node];
    int es = u >> 2;                 // edge slot within group (0..3)
    int le = u & 3;                  // 16 B chunk of the 64 B head-row
    const char* xwp = (const char*)xwb + ((size_t)hh * NN << 6) + (le << 4);

    float4 accA = make_float4(0.f, 0.f, 0.f, 0.f);
    float4 accB = make_float4(0.f, 0.f, 0.f, 0.f);
    float dsum = 0.f;

    for (int base = beg; base < end; base += 16) {
        int cnt = end - base; if (cnt > 16) cnt = 16;
        if (u < cnt) {
            int s = esrc[base + u];
            float w = __expf(lrelu(ash[s] + adh));
            dsum += w;
            sw[g][u] = make_float2(__int_as_float(s), w);
        }
        int iters = (cnt + 3) >> 2;
        for (int it = 0; it < iters; ++it) {
            int j = (it << 2) + es;
            bool ok = j < cnt;
            float2 sv = sw[g][ok ? j : 0];
            float wj = ok ? sv.y : 0.f;
            unsigned off = ok ? ((unsigned)__float_as_int(sv.x) << 6) : 0u;
            uint4 v = *(const uint4*)(xwp + off);
            accA.x = fmaf(wj, __uint_as_float(v.x << 16), accA.x);
            accA.y = fmaf(wj, __uint_as_float(v.x & 0xffff0000u), accA.y);
            accA.z = fmaf(wj, __uint_as_float(v.y << 16), accA.z);
            accA.w = fmaf(wj, __uint_as_float(v.y & 0xffff0000u), accA.w);
            accB.x = fmaf(wj, __uint_as_float(v.z << 16), accB.x);
            accB.y = fmaf(wj, __uint_as_float(v.z & 0xffff0000u), accB.y);
            accB.z = fmaf(wj, __uint_as_float(v.w << 16), accB.z);
            accB.w = fmaf(wj, __uint_as_float(v.w & 0xffff0000u), accB.w);
        }
    }
    // acc: reduce the 4 edge slots (xor bits 2..3 — stays within group)
#pragma unroll
    for (int off = 4; off <= 8; off <<= 1) {
        accA.x += __shfl_xor(accA.x, off);
        accA.y += __shfl_xor(accA.y, off);
        accA.z += __shfl_xor(accA.z, off);
        accA.w += __shfl_xor(accA.w, off);
        accB.x += __shfl_xor(accB.x, off);
        accB.y += __shfl_xor(accB.y, off);
        accB.z += __shfl_xor(accB.z, off);
        accB.w += __shfl_xor(accB.w, off);
    }
    // dsum: reduce all 16 lanes of the group (xor bits 0..3)
#pragma unroll
    for (int off = 1; off <= 8; off <<= 1) dsum += __shfl_xor(dsum, off);

    if (es == 0) {                   // u = 0..3 == le
        float inv = 1.f / dsum;
        float4 bb0 = ((const float4*)bias)[hh * 8 + le * 2];
        float4 bb1 = ((const float4*)bias)[hh * 8 + le * 2 + 1];
        float4 oA, oB;
        oA.x = fmaf(accA.x, inv, bb0.x);
        oA.y = fmaf(accA.y, inv, bb0.y);
        oA.z = fmaf(accA.z, inv, bb0.z);
        oA.w = fmaf(accA.w, inv, bb0.w);
        oB.x = fmaf(accB.x, inv, bb1.x);
        oB.y = fmaf(accB.y, inv, bb1.y);
        oB.z = fmaf(accB.z, inv, bb1.z);
        oB.w = fmaf(accB.w, inv, bb1.w);
        oA.x = oA.x > 0.f ? oA.x : expm1f(oA.x);
        oA.y = oA.y > 0.f ? oA.y : expm1f(oA.y);
        oA.z = oA.z > 0.f ? oA.z : expm1f(oA.z);
        oA.w = oA.w > 0.f ? oA.w : expm1f(oA.w);
        oB.x = oB.x > 0.f ? oB.x : expm1f(oB.x);
        oB.y = oB.y > 0.f ? oB.y : expm1f(oB.y);
        oB.z = oB.z > 0.f ? oB.z : expm1f(oB.z);
        oB.w = oB.w > 0.f ? oB.w : expm1f(oB.w);
        ((float4*)out)[(size_t)node * 32 + hh * 8 + le * 2] = oA;
        ((float4*)out)[(size_t)node * 32 + hh * 8 + le * 2 + 1] = oB;
    }
}

// ---------------- pooling + head ----------------
__global__ __launch_bounds__(128) void pool(
    const float* __restrict__ h1, const int* __restrict__ batch,
    float* __restrict__ sums, float* __restrict__ cnts) {
    int j = threadIdx.x;
    int n0 = blockIdx.x * 64;
    int n1 = n0 + 64; if (n1 > NN) n1 = NN;
    if (n0 >= NN) return;
    int cur = batch[n0];
    float local = 0.f;
    int cnt = 0;
    for (int n = n0; n < n1; ++n) {
        int g = batch[n];
        if (g != cur) {
            atomicAdd(&sums[cur * HC + j], local);
            if (j == 0) atomicAdd(&cnts[cur], (float)cnt);
            local = 0.f; cnt = 0; cur = g;
        }
        local += h1[(size_t)n * HC + j];
        ++cnt;
    }
    atomicAdd(&sums[cur * HC + j], local);
    if (j == 0) atomicAdd(&cnts[cur], (float)cnt);
}

__global__ __launch_bounds__(128) void head_out(
    const float* __restrict__ sums, const float* __restrict__ cnts,
    const float* __restrict__ lin_w, const float* __restrict__ lin_b,
    float* __restrict__ out) {
    int g = blockIdx.x;
    int j = threadIdx.x;
    float c = cnts[g];
    c = c > 1.f ? c : 1.f;
    float v = sums[g * HC + j] / c * lin_w[j];
    __shared__ float red[HC];
    red[j] = v;
    __syncthreads();
    for (int off = 64; off > 0; off >>= 1) {
        if (j < off) red[j] += red[j + off];
        __syncthreads();
    }
    if (j == 0) out[g] = red[0] + lin_b[0];
}

extern "C" void kernel_launch(void* const* d_in, const int* in_sizes, int n_in,
                              void* d_out, int out_size, void* d_ws, size_t ws_size,
                              hipStream_t stream) {
    const float* x   = (const float*)d_in[0];
    const int*   ei  = (const int*)d_in[1];
    const int*   bat = (const int*)d_in[2];
    const float* W0  = (const float*)d_in[3];
    const float* as0 = (const float*)d_in[4];
    const float* ad0 = (const float*)d_in[5];
    const float* b0  = (const float*)d_in[6];
    const float* W1  = (const float*)d_in[7];
    const float* as1 = (const float*)d_in[8];
    const float* ad1 = (const float*)d_in[9];
    const float* b1  = (const float*)d_in[10];
    const float* lw  = (const float*)d_in[11];
    const float* lb  = (const float*)d_in[12];
    float* out = (float*)d_out;

    char* w = (char*)d_ws;
    unsigned* xwb = (unsigned*)w; w += (size_t)NN * HC * 2;   // 12.8 MB bf16 (head-major)
    float* h0  = (float*)w;  w += (size_t)NN * HC * 4;        // 25.6 MB
    float* as_ = (float*)w;  w += (size_t)NN * HH * 4;        // head-major [h][n]
    float* ad_ = (float*)w;  w += (size_t)NN * HH * 4;
    int* row_start = (int*)w; w += (size_t)(NN + 1) * 4;
    int* bcur      = (int*)w; w += (size_t)NBKT * 4;
    int* bbase     = (int*)w; w += (size_t)NBKT * 4;
    int* esrc      = (int*)w; w += (size_t)NEDGE * 4;         // 6.6 MB
    uint2* pairs   = (uint2*)w; w += (size_t)NBKT * BCAP * 8; // 19.7 MB
    float* sums = (float*)w; w += (size_t)GG * HC * 4;
    float* cnts = (float*)w; w += (size_t)GG * 4;

    const int gb = (NN + GMT - 1) / GMT;
    const int ab = HH * APH;

    // ---- CSR build (shared by both layers) ----
    binit<<<1, 256, 0, stream>>>(bcur);
    bucketize<<<NB1, 256, 0, stream>>>(ei, bcur, pairs);
    bscan<<<1, 256, 0, stream>>>(bcur, bbase);
    debucket<<<NBKT, 512, 0, stream>>>(pairs, bcur, bbase, row_start, esrc);

    // ---- layer 0 ----
    gemm_alpha<<<gb, 256, 0, stream>>>(x, W0, as0, ad0, xwb, as_, ad_);
    aggregate<<<ab, 256, 0, stream>>>(esrc, row_start, as_, ad_, xwb, b0, h0);

    // ---- layer 1 ----
    gemm_alpha<<<gb, 256, 0, stream>>>(h0, W1, as1, ad1, xwb, as_, ad_);
    aggregate<<<ab, 256, 0, stream>>>(esrc, row_start, as_, ad_, xwb, b1, h0);

    // ---- pool + head ----
    hipMemsetAsync(sums, 0, ((size_t)GG * HC + GG) * 4, stream);
    pool<<<(NN + 63) / 64, 128, 0, stream>>>(h0, bat, sums, cnts);
    head_out<<<GG, 128, 0, stream>>>(sums, cnts, lw, lb, out);
}

// Round 16
// 278.575 us; speedup vs baseline: 1.0410x; 1.0410x over previous
//
#include <hip/hip_runtime.h>
#include <hip/hip_bf16.h>

#define NN 50000
#define EE 1600000
#define NEDGE (EE + NN)   // with self loops
#define HH 4
#define HC 128
#define GG 64
#define NBKT 196          // dst buckets of 256 nodes
#define BCAP 12544        // pairs capacity per bucket (mean 8163, +48 sigma)
#define BKE 2048          // edges per bucketize block
#define NB1 ((EE + BKE - 1) / BKE)
#define GB ((NN + 63) / 64)   // gemm blocks: 64 nodes per block

typedef short bf16x8 __attribute__((ext_vector_type(8)));
typedef float f32x4 __attribute__((ext_vector_type(4)));

__device__ __forceinline__ float lrelu(float x) { return fmaxf(x, 0.2f * x); }

__device__ __forceinline__ unsigned short f2bf(float f) {
    unsigned u = __float_as_uint(f);
    u = (u + 0x7fffu + ((u >> 16) & 1u)) >> 16;
    return (unsigned short)u;
}
__device__ __forceinline__ float bf2f(unsigned short h) {
    return __uint_as_float((unsigned)h << 16);
}

// ---------------- CSR build: bucketize -> bscan -> debucket ----------------
__global__ __launch_bounds__(256) void binit(int* __restrict__ bcur) {
    int t = blockIdx.x * 256 + threadIdx.x;
    if (t < NBKT) bcur[t] = t * BCAP;
}

// stage (d,s) pairs in LDS grouped by bucket, flush coalesced.
__global__ __launch_bounds__(256) void bucketize(const int* __restrict__ ei,
                                                 int* __restrict__ bcur,
                                                 uint2* __restrict__ pairs) {
    __shared__ int cnt[NBKT], off[NBKT], gbase[NBKT];
    __shared__ int wsum[4], woff[4];
    __shared__ uint2 stage[BKE];
    int t = threadIdx.x;
    int e0 = blockIdx.x * BKE;
    int n = EE - e0; if (n > BKE) n = BKE;
    for (int i = t; i < NBKT; i += 256) cnt[i] = 0;
    __syncthreads();
    unsigned dv[8], sv[8];
    int rk[8];
#pragma unroll
    for (int k = 0; k < 8; ++k) {
        int i = t + k * 256;
        if (i < n) {
            dv[k] = (unsigned)ei[EE + e0 + i];
            sv[k] = (unsigned)ei[e0 + i];
            rk[k] = atomicAdd(&cnt[dv[k] >> 8], 1);
        }
    }
    __syncthreads();
    {
        int v = (t < NBKT) ? cnt[t] : 0;
        int lane = t & 63, wv = t >> 6;
        int x = v;
#pragma unroll
        for (int o = 1; o < 64; o <<= 1) { int y = __shfl_up(x, o); if (lane >= o) x += y; }
        if (lane == 63) wsum[wv] = x;
        __syncthreads();
        if (t == 0) { int r = 0; for (int k2 = 0; k2 < 4; ++k2) { woff[k2] = r; r += wsum[k2]; } }
        __syncthreads();
        if (t < NBKT) off[t] = x - v + woff[wv];
    }
    __syncthreads();
#pragma unroll
    for (int k = 0; k < 8; ++k) {
        int i = t + k * 256;
        if (i < n) stage[off[dv[k] >> 8] + rk[k]] = make_uint2(dv[k], sv[k]);
    }
    __syncthreads();
    if (t < NBKT) { int c = cnt[t]; gbase[t] = c ? atomicAdd(&bcur[t], c) : 0; }
    __syncthreads();
    for (int i = t; i < n; i += 256) {
        uint2 pr = stage[i];
        int b = (int)(pr.x >> 8);
        pairs[(size_t)gbase[b] + (i - off[b])] = pr;
    }
}

__global__ __launch_bounds__(256) void bscan(const int* __restrict__ bcur,
                                             int* __restrict__ bbase) {
    int t = threadIdx.x;
    int v = 0;
    if (t < NBKT) {
        int pcnt = bcur[t] - t * BCAP;
        int nodes = NN - t * 256; if (nodes > 256) nodes = 256;
        v = pcnt + nodes;
    }
    int lane = t & 63, wv = t >> 6;
    int x = v;
#pragma unroll
    for (int o = 1; o < 64; o <<= 1) { int y = __shfl_up(x, o); if (lane >= o) x += y; }
    __shared__ int wsum[4], woff[4];
    if (lane == 63) wsum[wv] = x;
    __syncthreads();
    if (t == 0) { int r = 0; for (int k = 0; k < 4; ++k) { woff[k] = r; r += wsum[k]; } }
    __syncthreads();
    if (t < NBKT) bbase[t] = x - v + woff[wv];
}

__global__ __launch_bounds__(512) void debucket(const uint2* __restrict__ pairs,
                                                const int* __restrict__ bcur,
                                                const int* __restrict__ bbase,
                                                int* __restrict__ row_start,
                                                int* __restrict__ esrc) {
    __shared__ int cnt[256], off[256], cur[256];
    __shared__ int wsum[4], woff[4];
    __shared__ int stage[BCAP + 256];
    int b = blockIdx.x, t = threadIdx.x;
    int n0 = b * 256;
    int nnode = NN - n0; if (nnode > 256) nnode = 256;
    int pcnt = bcur[b] - b * BCAP;
    int base = bbase[b];
    if (t < 256) cnt[t] = 0;
    __syncthreads();
    for (int i = t; i < pcnt; i += 512)
        atomicAdd(&cnt[pairs[(size_t)b * BCAP + i].x & 255u], 1);
    __syncthreads();
    {
        int v = 0, x = 0;
        int lane = t & 63, wv = t >> 6;
        if (t < 256) {
            v = cnt[t] + (t < nnode ? 1 : 0);
            x = v;
#pragma unroll
            for (int o = 1; o < 64; o <<= 1) { int y = __shfl_up(x, o); if (lane >= o) x += y; }
            if (lane == 63) wsum[wv] = x;
        }
        __syncthreads();
        if (t == 0) { int r = 0; for (int k = 0; k < 4; ++k) { woff[k] = r; r += wsum[k]; } }
        __syncthreads();
        if (t < 256) off[t] = x - v + woff[wv];
    }
    __syncthreads();
    if (t < nnode) {
        int o = off[t];
        stage[o] = n0 + t;
        cur[t] = o + 1;
        row_start[n0 + t] = base + o;
    }
    __syncthreads();
    for (int i = t; i < pcnt; i += 512) {
        uint2 pr = pairs[(size_t)b * BCAP + i];
        int p = atomicAdd(&cur[pr.x & 255u], 1);
        stage[p] = (int)pr.y;
    }
    __syncthreads();
    int tot = pcnt + nnode;
    for (int i = t; i < tot; i += 512) esrc[base + i] = stage[i];
    if (b == NBKT - 1 && t == 0) row_start[NN] = NEDGE;
}

// ---------------- W prep: fp32 [k][c] -> bf16 hi/lo transposed [c][k] ----------------
__global__ __launch_bounds__(256) void wprep(const float* __restrict__ W,
                                             unsigned short* __restrict__ wt_hi,
                                             unsigned short* __restrict__ wt_lo) {
    int idx = blockIdx.x * 256 + threadIdx.x;   // k*128 + c
    int k = idx >> 7, c = idx & 127;
    float f = W[idx];
    unsigned short h = f2bf(f);
    wt_hi[c * 128 + k] = h;
    wt_lo[c * 128 + k] = f2bf(f - bf2f(h));
}

// ---------------- MFMA GEMM (X @ W) + per-head alpha dots ----------------
// split hi/lo compensation: X@W = Xh@Wh + Xl@Wh + Xh@Wl (fp32-quality).
// 64 nodes/block, 4 waves, 16 nodes/wave. D: col=lane&15, row=(lane>>4)*4+r.
__global__ __launch_bounds__(256) void gemm_mfma(
    const float* __restrict__ X,
    const unsigned short* __restrict__ wt_hi, const unsigned short* __restrict__ wt_lo,
    const float* __restrict__ a_src, const float* __restrict__ a_dst,
    unsigned short* __restrict__ xwb16, float* __restrict__ as_, float* __restrict__ ad_) {
    int wv = (int)(threadIdx.x >> 6);
    int lane = (int)(threadIdx.x & 63);
    int m = lane & 15;
    int kg = lane >> 4;
    int n0 = blockIdx.x * 64 + wv * 16;
    int nA = n0 + m;
    int nAc = nA < NN ? nA : 0;

    // A fragments: lane holds X[n0+m][kk*32 + kg*8 + j]
    bf16x8 a_hi[4], a_lo[4];
#pragma unroll
    for (int kk = 0; kk < 4; ++kk) {
        const float* px = X + (size_t)nAc * HC + kk * 32 + kg * 8;
        float4 x0 = *(const float4*)px;
        float4 x1 = *(const float4*)(px + 4);
        float xf[8] = {x0.x, x0.y, x0.z, x0.w, x1.x, x1.y, x1.z, x1.w};
        bf16x8 hv, lv;
#pragma unroll
        for (int j = 0; j < 8; ++j) {
            unsigned short hb = f2bf(xf[j]);
            hv[j] = (short)hb;
            lv[j] = (short)f2bf(xf[j] - bf2f(hb));
        }
        a_hi[kk] = hv; a_lo[kk] = lv;
    }

    f32x4 acc[8] = {};
#pragma unroll
    for (int kk = 0; kk < 4; ++kk) {
#pragma unroll
        for (int ct = 0; ct < 8; ++ct) {
            int wo = (ct * 16 + m) * HC + kk * 32 + kg * 8;
            bf16x8 bh = *(const bf16x8*)(wt_hi + wo);
            bf16x8 bl = *(const bf16x8*)(wt_lo + wo);
            acc[ct] = __builtin_amdgcn_mfma_f32_16x16x32_bf16(a_hi[kk], bh, acc[ct], 0, 0, 0);
            acc[ct] = __builtin_amdgcn_mfma_f32_16x16x32_bf16(a_lo[kk], bh, acc[ct], 0, 0, 0);
            acc[ct] = __builtin_amdgcn_mfma_f32_16x16x32_bf16(a_hi[kk], bl, acc[ct], 0, 0, 0);
        }
    }

    // xwb write: lane holds node n0+kg*4+r, col ct*16+m
#pragma unroll
    for (int ct = 0; ct < 8; ++ct) {
#pragma unroll
        for (int r = 0; r < 4; ++r) {
            int n = n0 + kg * 4 + r;
            if (n < NN) xwb16[(size_t)n * HC + ct * 16 + m] = f2bf(acc[ct][r]);
        }
    }

    // per-head alpha dots: head = ct>>1 (cols [32h,32h+32))
    float ps[HH][4], pd[HH][4];
#pragma unroll
    for (int hq = 0; hq < HH; ++hq)
#pragma unroll
        for (int r = 0; r < 4; ++r) { ps[hq][r] = 0.f; pd[hq][r] = 0.f; }
#pragma unroll
    for (int ct = 0; ct < 8; ++ct) {
        float av = a_src[ct * 16 + m];
        float dv = a_dst[ct * 16 + m];
        int hq = ct >> 1;
#pragma unroll
        for (int r = 0; r < 4; ++r) {
            ps[hq][r] = fmaf(acc[ct][r], av, ps[hq][r]);
            pd[hq][r] = fmaf(acc[ct][r], dv, pd[hq][r]);
        }
    }
#pragma unroll
    for (int o = 1; o <= 8; o <<= 1) {
#pragma unroll
        for (int hq = 0; hq < HH; ++hq)
#pragma unroll
            for (int r = 0; r < 4; ++r) {
                ps[hq][r] += __shfl_xor(ps[hq][r], o);
                pd[hq][r] += __shfl_xor(pd[hq][r], o);
            }
    }
    if (m == 0) {
#pragma unroll
        for (int r = 0; r < 4; ++r) {
            int n = n0 + kg * 4 + r;
            if (n < NN) {
#pragma unroll
                for (int hq = 0; hq < HH; ++hq) {
                    as_[n * HH + hq] = ps[hq][r];
                    ad_[n * HH + hq] = pd[hq][r];
                }
            }
        }
    }
}

// ---------------- fused segment softmax + aggregate + bias + ELU ----------------
// node-major (round-12 verified): 32-bit byte-offset gathers + 1-deep prefetch
#define SWSTR 66
__global__ __launch_bounds__(256) void aggregate(
    const int* __restrict__ esrc, const int* __restrict__ row_start,
    const float* __restrict__ as_, const float* __restrict__ ad_,
    const unsigned* __restrict__ xwb, const float* __restrict__ bias,
    float* __restrict__ out) {
    __shared__ float2 sw_all[4][4 * SWSTR];
    int wid = (int)(threadIdx.x >> 6);
    int node = blockIdx.x * 4 + wid;
    if (node >= NN) return;
    int lane = threadIdx.x & 63;
    float2* sw = &sw_all[wid][0];
    int beg = row_start[node];
    int end = row_start[node + 1];
    float4 ad = ((const float4*)ad_)[node];

    int sub = lane >> 4;
    int c8 = lane & 15;
    int h = c8 >> 2;
    const char* xwp = (const char*)xwb + (c8 << 4);
    const char* asp = (const char*)as_;
    float4 accA = make_float4(0.f, 0.f, 0.f, 0.f);
    float4 accB = make_float4(0.f, 0.f, 0.f, 0.f);
    float d0 = 0.f, d1 = 0.f, d2 = 0.f, d3 = 0.f;

    for (int base = beg; base < end; base += 64) {
        int i = base + lane;
        int cnt = end - base; if (cnt > 64) cnt = 64;
        if (i < end) {
            int s = esrc[i];
            float4 av = *(const float4*)(asp + ((unsigned)s << 4));
            float w0 = __expf(lrelu(av.x + ad.x));
            float w1 = __expf(lrelu(av.y + ad.y));
            float w2 = __expf(lrelu(av.z + ad.z));
            float w3 = __expf(lrelu(av.w + ad.w));
            d0 += w0; d1 += w1; d2 += w2; d3 += w3;
            float sf = __int_as_float(s);
            sw[0 * SWSTR + lane] = make_float2(sf, w0);
            sw[1 * SWSTR + lane] = make_float2(sf, w1);
            sw[2 * SWSTR + lane] = make_float2(sf, w2);
            sw[3 * SWSTR + lane] = make_float2(sf, w3);
        }
        int iters = (cnt + 3) >> 2;
        bool ok = sub < cnt;
        float2 sv = sw[h * SWSTR + (ok ? sub : 0)];
        float wj = ok ? sv.y : 0.f;
        unsigned row = ok ? ((unsigned)__float_as_int(sv.x) << 8) : 0u;
        uint4 v = *(const uint4*)(xwp + row);
        for (int it = 1; it <= iters; ++it) {
            int j1 = (it << 2) + sub;
            bool ok1 = j1 < cnt;
            float2 sv1 = sw[h * SWSTR + (ok1 ? j1 : 0)];
            float w1 = ok1 ? sv1.y : 0.f;
            unsigned row1 = ok1 ? ((unsigned)__float_as_int(sv1.x) << 8) : 0u;
            uint4 v1 = *(const uint4*)(xwp + row1);
            accA.x = fmaf(wj, __uint_as_float(v.x << 16), accA.x);
            accA.y = fmaf(wj, __uint_as_float(v.x & 0xffff0000u), accA.y);
            accA.z = fmaf(wj, __uint_as_float(v.y << 16), accA.z);
            accA.w = fmaf(wj, __uint_as_float(v.y & 0xffff0000u), accA.w);
            accB.x = fmaf(wj, __uint_as_float(v.z << 16), accB.x);
            accB.y = fmaf(wj, __uint_as_float(v.z & 0xffff0000u), accB.y);
            accB.z = fmaf(wj, __uint_as_float(v.w << 16), accB.z);
            accB.w = fmaf(wj, __uint_as_float(v.w & 0xffff0000u), accB.w);
            v = v1; wj = w1;
        }
    }
#pragma unroll
    for (int off = 16; off <= 32; off <<= 1) {
        accA.x += __shfl_xor(accA.x, off);
        accA.y += __shfl_xor(accA.y, off);
        accA.z += __shfl_xor(accA.z, off);
        accA.w += __shfl_xor(accA.w, off);
        accB.x += __shfl_xor(accB.x, off);
        accB.y += __shfl_xor(accB.y, off);
        accB.z += __shfl_xor(accB.z, off);
        accB.w += __shfl_xor(accB.w, off);
    }
#pragma unroll
    for (int off = 32; off; off >>= 1) {
        d0 += __shfl_xor(d0, off);
        d1 += __shfl_xor(d1, off);
        d2 += __shfl_xor(d2, off);
        d3 += __shfl_xor(d3, off);
    }
    if (sub == 0) {
        float dn = h == 0 ? d0 : (h == 1 ? d1 : (h == 2 ? d2 : d3));
        float inv = 1.f / dn;
        float4 bb0 = ((const float4*)bias)[c8 * 2];
        float4 bb1 = ((const float4*)bias)[c8 * 2 + 1];
        float4 oA, oB;
        oA.x = fmaf(accA.x, inv, bb0.x);
        oA.y = fmaf(accA.y, inv, bb0.y);
        oA.z = fmaf(accA.z, inv, bb0.z);
        oA.w = fmaf(accA.w, inv, bb0.w);
        oB.x = fmaf(accB.x, inv, bb1.x);
        oB.y = fmaf(accB.y, inv, bb1.y);
        oB.z = fmaf(accB.z, inv, bb1.z);
        oB.w = fmaf(accB.w, inv, bb1.w);
        oA.x = oA.x > 0.f ? oA.x : expm1f(oA.x);
        oA.y = oA.y > 0.f ? oA.y : expm1f(oA.y);
        oA.z = oA.z > 0.f ? oA.z : expm1f(oA.z);
        oA.w = oA.w > 0.f ? oA.w : expm1f(oA.w);
        oB.x = oB.x > 0.f ? oB.x : expm1f(oB.x);
        oB.y = oB.y > 0.f ? oB.y : expm1f(oB.y);
        oB.z = oB.z > 0.f ? oB.z : expm1f(oB.z);
        oB.w = oB.w > 0.f ? oB.w : expm1f(oB.w);
        ((float4*)out)[(size_t)node * 32 + c8 * 2] = oA;
        ((float4*)out)[(size_t)node * 32 + c8 * 2 + 1] = oB;
    }
}

// ---------------- pooling + head ----------------
__global__ __launch_bounds__(128) void pool(
    const float* __restrict__ h1, const int* __restrict__ batch,
    float* __restrict__ sums, float* __restrict__ cnts) {
    int j = threadIdx.x;
    int n0 = blockIdx.x * 64;
    int n1 = n0 + 64; if (n1 > NN) n1 = NN;
    if (n0 >= NN) return;
    int cur = batch[n0];
    float local = 0.f;
    int cnt = 0;
    for (int n = n0; n < n1; ++n) {
        int g = batch[n];
        if (g != cur) {
            atomicAdd(&sums[cur * HC + j], local);
            if (j == 0) atomicAdd(&cnts[cur], (float)cnt);
            local = 0.f; cnt = 0; cur = g;
        }
        local += h1[(size_t)n * HC + j];
        ++cnt;
    }
    atomicAdd(&sums[cur * HC + j], local);
    if (j == 0) atomicAdd(&cnts[cur], (float)cnt);
}

__global__ __launch_bounds__(128) void head_out(
    const float* __restrict__ sums, const float* __restrict__ cnts,
    const float* __restrict__ lin_w, const float* __restrict__ lin_b,
    float* __restrict__ out) {
    int g = blockIdx.x;
    int j = threadIdx.x;
    float c = cnts[g];
    c = c > 1.f ? c : 1.f;
    float v = sums[g * HC + j] / c * lin_w[j];
    __shared__ float red[HC];
    red[j] = v;
    __syncthreads();
    for (int off = 64; off > 0; off >>= 1) {
        if (j < off) red[j] += red[j + off];
        __syncthreads();
    }
    if (j == 0) out[g] = red[0] + lin_b[0];
}

extern "C" void kernel_launch(void* const* d_in, const int* in_sizes, int n_in,
                              void* d_out, int out_size, void* d_ws, size_t ws_size,
                              hipStream_t stream) {
    const float* x   = (const float*)d_in[0];
    const int*   ei  = (const int*)d_in[1];
    const int*   bat = (const int*)d_in[2];
    const float* W0  = (const float*)d_in[3];
    const float* as0 = (const float*)d_in[4];
    const float* ad0 = (const float*)d_in[5];
    const float* b0  = (const float*)d_in[6];
    const float* W1  = (const float*)d_in[7];
    const float* as1 = (const float*)d_in[8];
    const float* ad1 = (const float*)d_in[9];
    const float* b1  = (const float*)d_in[10];
    const float* lw  = (const float*)d_in[11];
    const float* lb  = (const float*)d_in[12];
    float* out = (float*)d_out;

    char* w = (char*)d_ws;
    unsigned* xwb = (unsigned*)w; w += (size_t)NN * HC * 2;   // 12.8 MB bf16
    float* h0  = (float*)w;  w += (size_t)NN * HC * 4;        // 25.6 MB
    float* as_ = (float*)w;  w += (size_t)NN * HH * 4;
    float* ad_ = (float*)w;  w += (size_t)NN * HH * 4;
    int* row_start = (int*)w; w += (size_t)(NN + 1) * 4;
    int* bcur      = (int*)w; w += (size_t)NBKT * 4;
    int* bbase     = (int*)w; w += (size_t)NBKT * 4;
    int* esrc      = (int*)w; w += (size_t)NEDGE * 4;         // 6.6 MB
    uint2* pairs   = (uint2*)w; w += (size_t)NBKT * BCAP * 8; // 19.7 MB
    unsigned short* wt0h = (unsigned short*)w; w += (size_t)HC * HC * 2;
    unsigned short* wt0l = (unsigned short*)w; w += (size_t)HC * HC * 2;
    unsigned short* wt1h = (unsigned short*)w; w += (size_t)HC * HC * 2;
    unsigned short* wt1l = (unsigned short*)w; w += (size_t)HC * HC * 2;
    float* sums = (float*)w; w += (size_t)GG * HC * 4;
    float* cnts = (float*)w; w += (size_t)GG * 4;

    const int ab = (NN + 3) / 4;

    // ---- W prep + CSR build (shared by both layers) ----
    wprep<<<(HC * HC) / 256, 256, 0, stream>>>(W0, wt0h, wt0l);
    wprep<<<(HC * HC) / 256, 256, 0, stream>>>(W1, wt1h, wt1l);
    binit<<<1, 256, 0, stream>>>(bcur);
    bucketize<<<NB1, 256, 0, stream>>>(ei, bcur, pairs);
    bscan<<<1, 256, 0, stream>>>(bcur, bbase);
    debucket<<<NBKT, 512, 0, stream>>>(pairs, bcur, bbase, row_start, esrc);

    // ---- layer 0 ----
    gemm_mfma<<<GB, 256, 0, stream>>>(x, wt0h, wt0l, as0, ad0,
                                      (unsigned short*)xwb, as_, ad_);
    aggregate<<<ab, 256, 0, stream>>>(esrc, row_start, as_, ad_, xwb, b0, h0);

    // ---- layer 1 ----
    gemm_mfma<<<GB, 256, 0, stream>>>(h0, wt1h, wt1l, as1, ad1,
                                      (unsigned short*)xwb, as_, ad_);
    aggregate<<<ab, 256, 0, stream>>>(esrc, row_start, as_, ad_, xwb, b1, h0);

    // ---- pool + head ----
    hipMemsetAsync(sums, 0, ((size_t)GG * HC + GG) * 4, stream);
    pool<<<(NN + 63) / 64, 128, 0, stream>>>(h0, bat, sums, cnts);
    head_out<<<GG, 128, 0, stream>>>(sums, cnts, lw, lb, out);
}

// Round 17
// 261.945 us; speedup vs baseline: 1.1071x; 1.0635x over previous
//
#include <hip/hip_runtime.h>
#include <hip/hip_bf16.h>

#define NN 50000
#define EE 1600000
#define NEDGE (EE + NN)   // with self loops
#define HH 4
#define HC 128
#define GG 64
#define GMT 64            // nodes per gemm block
#define NBKT 196          // dst buckets of 256 nodes
#define BCAP 12544        // pairs capacity per bucket (mean 8163, +48 sigma)
#define BKE 2048          // edges per bucketize block
#define NB1 ((EE + BKE - 1) / BKE)

__device__ __forceinline__ float lrelu(float x) { return fmaxf(x, 0.2f * x); }

// round-to-nearest-even f32 -> bf16 (as u16), pack two into a uint
__device__ __forceinline__ unsigned packbf2(float a, float b) {
    unsigned ua = __float_as_uint(a);
    ua = (ua + 0x7fffu + ((ua >> 16) & 1u)) >> 16;
    unsigned ub = __float_as_uint(b);
    ub = (ub + 0x7fffu + ((ub >> 16) & 1u)) >> 16;
    return ua | (ub << 16);
}

// ---------------- CSR build: bucketize -> bscan -> debucket ----------------
__global__ __launch_bounds__(256) void binit(int* __restrict__ bcur) {
    int t = blockIdx.x * 256 + threadIdx.x;
    if (t < NBKT) bcur[t] = t * BCAP;
}

// stage (d,s) pairs in LDS grouped by bucket, flush coalesced.
// rank trick: pass-1 atomicAdd returns each edge's rank -> no 2nd atomic pass.
__global__ __launch_bounds__(256) void bucketize(const int* __restrict__ ei,
                                                 int* __restrict__ bcur,
                                                 uint2* __restrict__ pairs) {
    __shared__ int cnt[NBKT], off[NBKT], gbase[NBKT];
    __shared__ int wsum[4], woff[4];
    __shared__ uint2 stage[BKE];
    int t = threadIdx.x;
    int e0 = blockIdx.x * BKE;
    int n = EE - e0; if (n > BKE) n = BKE;
    for (int i = t; i < NBKT; i += 256) cnt[i] = 0;
    __syncthreads();
    unsigned dv[8], sv[8];
    int rk[8];
#pragma unroll
    for (int k = 0; k < 8; ++k) {
        int i = t + k * 256;
        if (i < n) {
            dv[k] = (unsigned)ei[EE + e0 + i];
            sv[k] = (unsigned)ei[e0 + i];
            rk[k] = atomicAdd(&cnt[dv[k] >> 8], 1);
        }
    }
    __syncthreads();
    // exclusive scan of cnt -> off
    {
        int v = (t < NBKT) ? cnt[t] : 0;
        int lane = t & 63, wv = t >> 6;
        int x = v;
#pragma unroll
        for (int o = 1; o < 64; o <<= 1) { int y = __shfl_up(x, o); if (lane >= o) x += y; }
        if (lane == 63) wsum[wv] = x;
        __syncthreads();
        if (t == 0) { int r = 0; for (int k2 = 0; k2 < 4; ++k2) { woff[k2] = r; r += wsum[k2]; } }
        __syncthreads();
        if (t < NBKT) off[t] = x - v + woff[wv];
    }
    __syncthreads();
#pragma unroll
    for (int k = 0; k < 8; ++k) {
        int i = t + k * 256;
        if (i < n) stage[off[dv[k] >> 8] + rk[k]] = make_uint2(dv[k], sv[k]);
    }
    __syncthreads();
    if (t < NBKT) { int c = cnt[t]; gbase[t] = c ? atomicAdd(&bcur[t], c) : 0; }
    __syncthreads();
    // coalesced flush: consecutive i within a bucket -> consecutive global
    for (int i = t; i < n; i += 256) {
        uint2 pr = stage[i];
        int b = (int)(pr.x >> 8);
        pairs[(size_t)gbase[b] + (i - off[b])] = pr;
    }
}

// exclusive scan of per-bucket totals (pairs + self loops) -> bucket bases
__global__ __launch_bounds__(256) void bscan(const int* __restrict__ bcur,
                                             int* __restrict__ bbase) {
    int t = threadIdx.x;
    int v = 0;
    if (t < NBKT) {
        int pcnt = bcur[t] - t * BCAP;
        int nodes = NN - t * 256; if (nodes > 256) nodes = 256;
        v = pcnt + nodes;
    }
    int lane = t & 63, wv = t >> 6;
    int x = v;
#pragma unroll
    for (int o = 1; o < 64; o <<= 1) { int y = __shfl_up(x, o); if (lane >= o) x += y; }
    __shared__ int wsum[4], woff[4];
    if (lane == 63) wsum[wv] = x;
    __syncthreads();
    if (t == 0) { int r = 0; for (int k = 0; k < 4; ++k) { woff[k] = r; r += wsum[k]; } }
    __syncthreads();
    if (t < NBKT) bbase[t] = x - v + woff[wv];
}

// per bucket: derive per-node offsets from the bucket's own pairs,
// write row_start AND node-exact esrc segment (built in LDS, flushed contiguous)
__global__ __launch_bounds__(512) void debucket(const uint2* __restrict__ pairs,
                                                const int* __restrict__ bcur,
                                                const int* __restrict__ bbase,
                                                int* __restrict__ row_start,
                                                int* __restrict__ esrc) {
    __shared__ int cnt[256], off[256], cur[256];
    __shared__ int wsum[4], woff[4];
    __shared__ int stage[BCAP + 256];
    int b = blockIdx.x, t = threadIdx.x;
    int n0 = b * 256;
    int nnode = NN - n0; if (nnode > 256) nnode = 256;
    int pcnt = bcur[b] - b * BCAP;
    int base = bbase[b];
    if (t < 256) cnt[t] = 0;
    __syncthreads();
    // phase 1: per-node counts
    for (int i = t; i < pcnt; i += 512)
        atomicAdd(&cnt[pairs[(size_t)b * BCAP + i].x & 255u], 1);
    __syncthreads();
    // phase 2: exclusive scan of (cnt[j] + self-loop)
    {
        int v = 0, x = 0;
        int lane = t & 63, wv = t >> 6;
        if (t < 256) {
            v = cnt[t] + (t < nnode ? 1 : 0);
            x = v;
#pragma unroll
            for (int o = 1; o < 64; o <<= 1) { int y = __shfl_up(x, o); if (lane >= o) x += y; }
            if (lane == 63) wsum[wv] = x;
        }
        __syncthreads();
        if (t == 0) { int r = 0; for (int k = 0; k < 4; ++k) { woff[k] = r; r += wsum[k]; } }
        __syncthreads();
        if (t < 256) off[t] = x - v + woff[wv];
    }
    __syncthreads();
    // phase 3: self loop first, then pairs
    if (t < nnode) {
        int o = off[t];
        stage[o] = n0 + t;
        cur[t] = o + 1;
        row_start[n0 + t] = base + o;
    }
    __syncthreads();
    for (int i = t; i < pcnt; i += 512) {
        uint2 pr = pairs[(size_t)b * BCAP + i];
        int p = atomicAdd(&cur[pr.x & 255u], 1);
        stage[p] = (int)pr.y;
    }
    __syncthreads();
    // phase 4: contiguous flush
    int tot = pcnt + nnode;
    for (int i = t; i < tot; i += 512) esrc[base + i] = stage[i];
    if (b == NBKT - 1 && t == 0) row_start[NN] = NEDGE;
}

// ---------------- GEMM (X @ W) + per-head alpha dots; bf16-packed output ----------------
__global__ __launch_bounds__(256) void gemm_alpha(
    const float* __restrict__ X, const float* __restrict__ W,
    const float* __restrict__ a_src, const float* __restrict__ a_dst,
    unsigned* __restrict__ xwb, float* __restrict__ as_, float* __restrict__ ad_) {
    __shared__ float xs[GMT][HC + 4];
    int tid = threadIdx.x;
    int n0 = blockIdx.x * GMT;
    for (int i = tid; i < GMT * (HC / 4); i += 256) {
        int r = i >> 5, c4 = i & 31;
        int n = n0 + r;
        float4 v = (n < NN) ? ((const float4*)X)[(size_t)n * 32 + c4]
                            : make_float4(0.f, 0.f, 0.f, 0.f);
        *(float4*)&xs[r][c4 * 4] = v;
    }
    __syncthreads();

    int jg = tid & 31;
    int ng = tid >> 5;
    float4 acc[8] = {};
    for (int k = 0; k < HC; k += 4) {
        float4 wr[4];
#pragma unroll
        for (int dk = 0; dk < 4; ++dk) wr[dk] = ((const float4*)W)[(k + dk) * 32 + jg];
#pragma unroll
        for (int r = 0; r < 8; ++r) {
            float4 xv = *(const float4*)&xs[ng * 8 + r][k];
            acc[r].x = fmaf(xv.x, wr[0].x, acc[r].x);
            acc[r].y = fmaf(xv.x, wr[0].y, acc[r].y);
            acc[r].z = fmaf(xv.x, wr[0].z, acc[r].z);
            acc[r].w = fmaf(xv.x, wr[0].w, acc[r].w);
            acc[r].x = fmaf(xv.y, wr[1].x, acc[r].x);
            acc[r].y = fmaf(xv.y, wr[1].y, acc[r].y);
            acc[r].z = fmaf(xv.y, wr[1].z, acc[r].z);
            acc[r].w = fmaf(xv.y, wr[1].w, acc[r].w);
            acc[r].x = fmaf(xv.z, wr[2].x, acc[r].x);
            acc[r].y = fmaf(xv.z, wr[2].y, acc[r].y);
            acc[r].z = fmaf(xv.z, wr[2].z, acc[r].z);
            acc[r].w = fmaf(xv.z, wr[2].w, acc[r].w);
            acc[r].x = fmaf(xv.w, wr[3].x, acc[r].x);
            acc[r].y = fmaf(xv.w, wr[3].y, acc[r].y);
            acc[r].z = fmaf(xv.w, wr[3].z, acc[r].z);
            acc[r].w = fmaf(xv.w, wr[3].w, acc[r].w);
        }
    }
    float4 asv = ((const float4*)a_src)[jg];
    float4 adv = ((const float4*)a_dst)[jg];
#pragma unroll
    for (int r = 0; r < 8; ++r) {
        int n = n0 + ng * 8 + r;
        float ps = acc[r].x * asv.x + acc[r].y * asv.y + acc[r].z * asv.z + acc[r].w * asv.w;
        float pd = acc[r].x * adv.x + acc[r].y * adv.y + acc[r].z * adv.z + acc[r].w * adv.w;
        ps += __shfl_xor(ps, 1); pd += __shfl_xor(pd, 1);
        ps += __shfl_xor(ps, 2); pd += __shfl_xor(pd, 2);
        ps += __shfl_xor(ps, 4); pd += __shfl_xor(pd, 4);
        if (n < NN) {
            ((uint2*)xwb)[(size_t)n * 32 + jg] =
                make_uint2(packbf2(acc[r].x, acc[r].y), packbf2(acc[r].z, acc[r].w));
            if ((jg & 7) == 0) {
                int h = jg >> 3;
                as_[n * HH + h] = ps;
                ad_[n * HH + h] = pd;
            }
        }
    }
}

// ---------------- fused segment softmax + aggregate + bias + ELU ----------------
// node-major; 32-bit byte-offset gathers + 1-deep prefetch; per-head
// denominator folded into the inner loop (dloc += wj), reduced with the
// same xor16/32 rounds as acc — deletes the 24-bpermute dsum reduction.
#define SWSTR 66
__global__ __launch_bounds__(256) void aggregate(
    const int* __restrict__ esrc, const int* __restrict__ row_start,
    const float* __restrict__ as_, const float* __restrict__ ad_,
    const unsigned* __restrict__ xwb, const float* __restrict__ bias,
    float* __restrict__ out) {
    __shared__ float2 sw_all[4][4 * SWSTR];
    int wid = (int)(threadIdx.x >> 6);
    int node = blockIdx.x * 4 + wid;
    if (node >= NN) return;
    int lane = threadIdx.x & 63;
    float2* sw = &sw_all[wid][0];
    int beg = row_start[node];
    int end = row_start[node + 1];
    float4 ad = ((const float4*)ad_)[node];

    int sub = lane >> 4;    // edge slot 0..3
    int c8 = lane & 15;     // cols c8*8 .. c8*8+7
    int h = c8 >> 2;        // head of those cols
    const char* xwp = (const char*)xwb + (c8 << 4);
    const char* asp = (const char*)as_;
    float4 accA = make_float4(0.f, 0.f, 0.f, 0.f);
    float4 accB = make_float4(0.f, 0.f, 0.f, 0.f);
    float dloc = 0.f;

    for (int base = beg; base < end; base += 64) {
        int i = base + lane;
        int cnt = end - base; if (cnt > 64) cnt = 64;
        if (i < end) {
            int s = esrc[i];
            float4 av = *(const float4*)(asp + ((unsigned)s << 4));
            float w0 = __expf(lrelu(av.x + ad.x));
            float w1 = __expf(lrelu(av.y + ad.y));
            float w2 = __expf(lrelu(av.z + ad.z));
            float w3 = __expf(lrelu(av.w + ad.w));
            float sf = __int_as_float(s);
            sw[0 * SWSTR + lane] = make_float2(sf, w0);
            sw[1 * SWSTR + lane] = make_float2(sf, w1);
            sw[2 * SWSTR + lane] = make_float2(sf, w2);
            sw[3 * SWSTR + lane] = make_float2(sf, w3);
        }
        int iters = (cnt + 3) >> 2;
        // prologue: group 0
        bool ok = sub < cnt;
        float2 sv = sw[h * SWSTR + (ok ? sub : 0)];
        float wj = ok ? sv.y : 0.f;
        unsigned row = ok ? ((unsigned)__float_as_int(sv.x) << 8) : 0u;
        uint4 v = *(const uint4*)(xwp + row);
        for (int it = 1; it <= iters; ++it) {
            // prefetch group `it` (clamped-safe on the last pass)
            int j1 = (it << 2) + sub;
            bool ok1 = j1 < cnt;
            float2 sv1 = sw[h * SWSTR + (ok1 ? j1 : 0)];
            float w1 = ok1 ? sv1.y : 0.f;
            unsigned row1 = ok1 ? ((unsigned)__float_as_int(sv1.x) << 8) : 0u;
            uint4 v1 = *(const uint4*)(xwp + row1);
            // consume group `it-1`
            dloc += wj;
            accA.x = fmaf(wj, __uint_as_float(v.x << 16), accA.x);
            accA.y = fmaf(wj, __uint_as_float(v.x & 0xffff0000u), accA.y);
            accA.z = fmaf(wj, __uint_as_float(v.y << 16), accA.z);
            accA.w = fmaf(wj, __uint_as_float(v.y & 0xffff0000u), accA.w);
            accB.x = fmaf(wj, __uint_as_float(v.z << 16), accB.x);
            accB.y = fmaf(wj, __uint_as_float(v.z & 0xffff0000u), accB.y);
            accB.z = fmaf(wj, __uint_as_float(v.w << 16), accB.z);
            accB.w = fmaf(wj, __uint_as_float(v.w & 0xffff0000u), accB.w);
            v = v1; wj = w1;
        }
    }
#pragma unroll
    for (int off = 16; off <= 32; off <<= 1) {
        accA.x += __shfl_xor(accA.x, off);
        accA.y += __shfl_xor(accA.y, off);
        accA.z += __shfl_xor(accA.z, off);
        accA.w += __shfl_xor(accA.w, off);
        accB.x += __shfl_xor(accB.x, off);
        accB.y += __shfl_xor(accB.y, off);
        accB.z += __shfl_xor(accB.z, off);
        accB.w += __shfl_xor(accB.w, off);
        dloc += __shfl_xor(dloc, off);
    }
    if (sub == 0) {
        float inv = 1.f / dloc;
        float4 bb0 = ((const float4*)bias)[c8 * 2];
        float4 bb1 = ((const float4*)bias)[c8 * 2 + 1];
        float4 oA, oB;
        oA.x = fmaf(accA.x, inv, bb0.x);
        oA.y = fmaf(accA.y, inv, bb0.y);
        oA.z = fmaf(accA.z, inv, bb0.z);
        oA.w = fmaf(accA.w, inv, bb0.w);
        oB.x = fmaf(accB.x, inv, bb1.x);
        oB.y = fmaf(accB.y, inv, bb1.y);
        oB.z = fmaf(accB.z, inv, bb1.z);
        oB.w = fmaf(accB.w, inv, bb1.w);
        oA.x = oA.x > 0.f ? oA.x : expm1f(oA.x);
        oA.y = oA.y > 0.f ? oA.y : expm1f(oA.y);
        oA.z = oA.z > 0.f ? oA.z : expm1f(oA.z);
        oA.w = oA.w > 0.f ? oA.w : expm1f(oA.w);
        oB.x = oB.x > 0.f ? oB.x : expm1f(oB.x);
        oB.y = oB.y > 0.f ? oB.y : expm1f(oB.y);
        oB.z = oB.z > 0.f ? oB.z : expm1f(oB.z);
        oB.w = oB.w > 0.f ? oB.w : expm1f(oB.w);
        ((float4*)out)[(size_t)node * 32 + c8 * 2] = oA;
        ((float4*)out)[(size_t)node * 32 + c8 * 2 + 1] = oB;
    }
}

// ---------------- pooling + head ----------------
__global__ __launch_bounds__(128) void pool(
    const float* __restrict__ h1, const int* __restrict__ batch,
    float* __restrict__ sums, float* __restrict__ cnts) {
    int j = threadIdx.x;
    int n0 = blockIdx.x * 64;
    int n1 = n0 + 64; if (n1 > NN) n1 = NN;
    if (n0 >= NN) return;
    int cur = batch[n0];
    float local = 0.f;
    int cnt = 0;
    for (int n = n0; n < n1; ++n) {
        int g = batch[n];
        if (g != cur) {
            atomicAdd(&sums[cur * HC + j], local);
            if (j == 0) atomicAdd(&cnts[cur], (float)cnt);
            local = 0.f; cnt = 0; cur = g;
        }
        local += h1[(size_t)n * HC + j];
        ++cnt;
    }
    atomicAdd(&sums[cur * HC + j], local);
    if (j == 0) atomicAdd(&cnts[cur], (float)cnt);
}

__global__ __launch_bounds__(128) void head_out(
    const float* __restrict__ sums, const float* __restrict__ cnts,
    const float* __restrict__ lin_w, const float* __restrict__ lin_b,
    float* __restrict__ out) {
    int g = blockIdx.x;
    int j = threadIdx.x;
    float c = cnts[g];
    c = c > 1.f ? c : 1.f;
    float v = sums[g * HC + j] / c * lin_w[j];
    __shared__ float red[HC];
    red[j] = v;
    __syncthreads();
    for (int off = 64; off > 0; off >>= 1) {
        if (j < off) red[j] += red[j + off];
        __syncthreads();
    }
    if (j == 0) out[g] = red[0] + lin_b[0];
}

extern "C" void kernel_launch(void* const* d_in, const int* in_sizes, int n_in,
                              void* d_out, int out_size, void* d_ws, size_t ws_size,
                              hipStream_t stream) {
    const float* x   = (const float*)d_in[0];
    const int*   ei  = (const int*)d_in[1];
    const int*   bat = (const int*)d_in[2];
    const float* W0  = (const float*)d_in[3];
    const float* as0 = (const float*)d_in[4];
    const float* ad0 = (const float*)d_in[5];
    const float* b0  = (const float*)d_in[6];
    const float* W1  = (const float*)d_in[7];
    const float* as1 = (const float*)d_in[8];
    const float* ad1 = (const float*)d_in[9];
    const float* b1  = (const float*)d_in[10];
    const float* lw  = (const float*)d_in[11];
    const float* lb  = (const float*)d_in[12];
    float* out = (float*)d_out;

    char* w = (char*)d_ws;
    unsigned* xwb = (unsigned*)w; w += (size_t)NN * HC * 2;   // 12.8 MB bf16
    float* h0  = (float*)w;  w += (size_t)NN * HC * 4;        // 25.6 MB
    float* as_ = (float*)w;  w += (size_t)NN * HH * 4;
    float* ad_ = (float*)w;  w += (size_t)NN * HH * 4;
    int* row_start = (int*)w; w += (size_t)(NN + 1) * 4;
    int* bcur      = (int*)w; w += (size_t)NBKT * 4;
    int* bbase     = (int*)w; w += (size_t)NBKT * 4;
    int* esrc      = (int*)w; w += (size_t)NEDGE * 4;         // 6.6 MB
    uint2* pairs   = (uint2*)w; w += (size_t)NBKT * BCAP * 8; // 19.7 MB
    float* sums = (float*)w; w += (size_t)GG * HC * 4;
    float* cnts = (float*)w; w += (size_t)GG * 4;

    const int gb = (NN + GMT - 1) / GMT;
    const int ab = (NN + 3) / 4;

    // ---- CSR build (shared by both layers) ----
    binit<<<1, 256, 0, stream>>>(bcur);
    bucketize<<<NB1, 256, 0, stream>>>(ei, bcur, pairs);
    bscan<<<1, 256, 0, stream>>>(bcur, bbase);
    debucket<<<NBKT, 512, 0, stream>>>(pairs, bcur, bbase, row_start, esrc);

    // ---- layer 0 ----
    gemm_alpha<<<gb, 256, 0, stream>>>(x, W0, as0, ad0, xwb, as_, ad_);
    aggregate<<<ab, 256, 0, stream>>>(esrc, row_start, as_, ad_, xwb, b0, h0);

    // ---- layer 1 ----
    gemm_alpha<<<gb, 256, 0, stream>>>(h0, W1, as1, ad1, xwb, as_, ad_);
    aggregate<<<ab, 256, 0, stream>>>(esrc, row_start, as_, ad_, xwb, b1, h0);

    // ---- pool + head ----
    hipMemsetAsync(sums, 0, ((size_t)GG * HC + GG) * 4, stream);
    pool<<<(NN + 63) / 64, 128, 0, stream>>>(h0, bat, sums, cnts);
    head_out<<<GG, 128, 0, stream>>>(sums, cnts, lw, lb, out);
}

// Round 18
// 249.337 us; speedup vs baseline: 1.1631x; 1.0506x over previous
//
#include <hip/hip_runtime.h>
#include <hip/hip_bf16.h>

#define NN 50000
#define EE 1600000
#define NEDGE (EE + NN)   // with self loops
#define HH 4
#define HC 128
#define GG 64
#define GMT 64            // nodes per gemm block
#define NBKT 196          // dst buckets of 256 nodes
#define BCAP 12544        // pairs capacity per bucket (mean 8163, +48 sigma)
#define BKE 2048          // edges per bucketize block
#define NB1 ((EE + BKE - 1) / BKE)          // 782
#define GB ((NN + GMT - 1) / GMT)           // 782 (== NB1)

__device__ __forceinline__ float lrelu(float x) { return fmaxf(x, 0.2f * x); }

__device__ __forceinline__ unsigned packbf2(float a, float b) {
    unsigned ua = __float_as_uint(a);
    ua = (ua + 0x7fffu + ((ua >> 16) & 1u)) >> 16;
    unsigned ub = __float_as_uint(b);
    ub = (ub + 0x7fffu + ((ub >> 16) & 1u)) >> 16;
    return ua | (ub << 16);
}

__global__ __launch_bounds__(256) void binit(int* __restrict__ bcur) {
    int t = blockIdx.x * 256 + threadIdx.x;
    if (t < NBKT) bcur[t] = t * BCAP;
}

// ---------------- merged dispatch: gemm L0 (even blocks) || bucketize (odd) ----------------
__global__ __launch_bounds__(256) void g0bkt(
    const float* __restrict__ X, const float* __restrict__ W,
    const float* __restrict__ a_src, const float* __restrict__ a_dst,
    unsigned* __restrict__ xwb, float* __restrict__ as_, float* __restrict__ ad_,
    const int* __restrict__ ei, int* __restrict__ bcur, uint2* __restrict__ pairs) {
    __shared__ union U {
        float xs[GMT][HC + 4];
        struct {
            int cnt[NBKT], off[NBKT], gbase[NBKT];
            int wsum[4], woff[4];
            uint2 stage[BKE];
        } b;
    } u;
    int t = threadIdx.x;
    int id = (int)(blockIdx.x >> 1);

    if ((blockIdx.x & 1) == 0) {
        // ---------------- gemm branch ----------------
        int n0 = id * GMT;
        for (int i = t; i < GMT * (HC / 4); i += 256) {
            int r = i >> 5, c4 = i & 31;
            int n = n0 + r;
            float4 v = (n < NN) ? ((const float4*)X)[(size_t)n * 32 + c4]
                                : make_float4(0.f, 0.f, 0.f, 0.f);
            *(float4*)&u.xs[r][c4 * 4] = v;
        }
        __syncthreads();
        int jg = t & 31;
        int ng = t >> 5;
        float4 acc[8] = {};
        for (int k = 0; k < HC; k += 4) {
            float4 wr[4];
#pragma unroll
            for (int dk = 0; dk < 4; ++dk) wr[dk] = ((const float4*)W)[(k + dk) * 32 + jg];
#pragma unroll
            for (int r = 0; r < 8; ++r) {
                float4 xv = *(const float4*)&u.xs[ng * 8 + r][k];
                acc[r].x = fmaf(xv.x, wr[0].x, acc[r].x);
                acc[r].y = fmaf(xv.x, wr[0].y, acc[r].y);
                acc[r].z = fmaf(xv.x, wr[0].z, acc[r].z);
                acc[r].w = fmaf(xv.x, wr[0].w, acc[r].w);
                acc[r].x = fmaf(xv.y, wr[1].x, acc[r].x);
                acc[r].y = fmaf(xv.y, wr[1].y, acc[r].y);
                acc[r].z = fmaf(xv.y, wr[1].z, acc[r].z);
                acc[r].w = fmaf(xv.y, wr[1].w, acc[r].w);
                acc[r].x = fmaf(xv.z, wr[2].x, acc[r].x);
                acc[r].y = fmaf(xv.z, wr[2].y, acc[r].y);
                acc[r].z = fmaf(xv.z, wr[2].z, acc[r].z);
                acc[r].w = fmaf(xv.z, wr[2].w, acc[r].w);
                acc[r].x = fmaf(xv.w, wr[3].x, acc[r].x);
                acc[r].y = fmaf(xv.w, wr[3].y, acc[r].y);
                acc[r].z = fmaf(xv.w, wr[3].z, acc[r].z);
                acc[r].w = fmaf(xv.w, wr[3].w, acc[r].w);
            }
        }
        float4 asv = ((const float4*)a_src)[jg];
        float4 adv = ((const float4*)a_dst)[jg];
#pragma unroll
        for (int r = 0; r < 8; ++r) {
            int n = n0 + ng * 8 + r;
            float ps = acc[r].x * asv.x + acc[r].y * asv.y + acc[r].z * asv.z + acc[r].w * asv.w;
            float pd = acc[r].x * adv.x + acc[r].y * adv.y + acc[r].z * adv.z + acc[r].w * adv.w;
            ps += __shfl_xor(ps, 1); pd += __shfl_xor(pd, 1);
            ps += __shfl_xor(ps, 2); pd += __shfl_xor(pd, 2);
            ps += __shfl_xor(ps, 4); pd += __shfl_xor(pd, 4);
            if (n < NN) {
                ((uint2*)xwb)[(size_t)n * 32 + jg] =
                    make_uint2(packbf2(acc[r].x, acc[r].y), packbf2(acc[r].z, acc[r].w));
                if ((jg & 7) == 0) {
                    int h = jg >> 3;
                    as_[n * HH + h] = ps;
                    ad_[n * HH + h] = pd;
                }
            }
        }
    } else {
        // ---------------- bucketize branch ----------------
        int e0 = id * BKE;
        int n = EE - e0; if (n > BKE) n = BKE;
        for (int i = t; i < NBKT; i += 256) u.b.cnt[i] = 0;
        __syncthreads();
        unsigned dv[8], sv[8];
        int rk[8];
#pragma unroll
        for (int k = 0; k < 8; ++k) {
            int i = t + k * 256;
            if (i < n) {
                dv[k] = (unsigned)ei[EE + e0 + i];
                sv[k] = (unsigned)ei[e0 + i];
                rk[k] = atomicAdd(&u.b.cnt[dv[k] >> 8], 1);
            }
        }
        __syncthreads();
        {
            int v = (t < NBKT) ? u.b.cnt[t] : 0;
            int lane = t & 63, wv = t >> 6;
            int x = v;
#pragma unroll
            for (int o = 1; o < 64; o <<= 1) { int y = __shfl_up(x, o); if (lane >= o) x += y; }
            if (lane == 63) u.b.wsum[wv] = x;
            __syncthreads();
            if (t == 0) { int r = 0; for (int k2 = 0; k2 < 4; ++k2) { u.b.woff[k2] = r; r += u.b.wsum[k2]; } }
            __syncthreads();
            if (t < NBKT) u.b.off[t] = x - v + u.b.woff[wv];
        }
        __syncthreads();
#pragma unroll
        for (int k = 0; k < 8; ++k) {
            int i = t + k * 256;
            if (i < n) u.b.stage[u.b.off[dv[k] >> 8] + rk[k]] = make_uint2(dv[k], sv[k]);
        }
        __syncthreads();
        if (t < NBKT) { int c = u.b.cnt[t]; u.b.gbase[t] = c ? atomicAdd(&bcur[t], c) : 0; }
        __syncthreads();
        for (int i = t; i < n; i += 256) {
            uint2 pr = u.b.stage[i];
            int b = (int)(pr.x >> 8);
            pairs[(size_t)u.b.gbase[b] + (i - u.b.off[b])] = pr;
        }
    }
}

// ---------------- debucket (computes its own bucket base; bscan deleted) ----------------
__global__ __launch_bounds__(512) void debucket(const uint2* __restrict__ pairs,
                                                const int* __restrict__ bcur,
                                                int* __restrict__ row_start,
                                                int* __restrict__ esrc) {
    __shared__ int cnt[256], off[256], cur[256];
    __shared__ int wsum[4], woff[4];
    __shared__ int wred[8];
    __shared__ int stage[BCAP + 256];
    int b = blockIdx.x, t = threadIdx.x;
    int n0 = b * 256;
    int nnode = NN - n0; if (nnode > 256) nnode = 256;
    int pcnt = bcur[b] - b * BCAP;

    // bucket base = sum over i<b of (pairs_i + nodes_i)
    int base;
    {
        int v = 0;
        if (t < b) {
            int pc = bcur[t] - t * BCAP;
            int nd = (t < NBKT - 1) ? 256 : (NN - (NBKT - 1) * 256);
            v = pc + nd;
        }
        int lane = t & 63, wv = t >> 6;
#pragma unroll
        for (int o = 1; o < 64; o <<= 1) v += __shfl_xor(v, o);
        if (lane == 0) wred[wv] = v;
        __syncthreads();
        if (t == 0) { int s = 0; for (int k = 0; k < 8; ++k) s += wred[k]; wred[0] = s; }
        __syncthreads();
        base = wred[0];
    }
    __syncthreads();
    if (t < 256) cnt[t] = 0;
    __syncthreads();
    for (int i = t; i < pcnt; i += 512)
        atomicAdd(&cnt[pairs[(size_t)b * BCAP + i].x & 255u], 1);
    __syncthreads();
    {
        int v = 0, x = 0;
        int lane = t & 63, wv = t >> 6;
        if (t < 256) {
            v = cnt[t] + (t < nnode ? 1 : 0);
            x = v;
#pragma unroll
            for (int o = 1; o < 64; o <<= 1) { int y = __shfl_up(x, o); if (lane >= o) x += y; }
            if (lane == 63) wsum[wv] = x;
        }
        __syncthreads();
        if (t == 0) { int r = 0; for (int k = 0; k < 4; ++k) { woff[k] = r; r += wsum[k]; } }
        __syncthreads();
        if (t < 256) off[t] = x - v + woff[wv];
    }
    __syncthreads();
    if (t < nnode) {
        int o = off[t];
        stage[o] = n0 + t;
        cur[t] = o + 1;
        row_start[n0 + t] = base + o;
    }
    __syncthreads();
    for (int i = t; i < pcnt; i += 512) {
        uint2 pr = pairs[(size_t)b * BCAP + i];
        int p = atomicAdd(&cur[pr.x & 255u], 1);
        stage[p] = (int)pr.y;
    }
    __syncthreads();
    int tot = pcnt + nnode;
    for (int i = t; i < tot; i += 512) esrc[base + i] = stage[i];
    if (b == NBKT - 1 && t == 0) row_start[NN] = NEDGE;
}

// ---------------- GEMM (X @ W) + per-head alpha dots (layer 1) ----------------
__global__ __launch_bounds__(256) void gemm_alpha(
    const float* __restrict__ X, const float* __restrict__ W,
    const float* __restrict__ a_src, const float* __restrict__ a_dst,
    unsigned* __restrict__ xwb, float* __restrict__ as_, float* __restrict__ ad_) {
    __shared__ float xs[GMT][HC + 4];
    int tid = threadIdx.x;
    int n0 = blockIdx.x * GMT;
    for (int i = tid; i < GMT * (HC / 4); i += 256) {
        int r = i >> 5, c4 = i & 31;
        int n = n0 + r;
        float4 v = (n < NN) ? ((const float4*)X)[(size_t)n * 32 + c4]
                            : make_float4(0.f, 0.f, 0.f, 0.f);
        *(float4*)&xs[r][c4 * 4] = v;
    }
    __syncthreads();

    int jg = tid & 31;
    int ng = tid >> 5;
    float4 acc[8] = {};
    for (int k = 0; k < HC; k += 4) {
        float4 wr[4];
#pragma unroll
        for (int dk = 0; dk < 4; ++dk) wr[dk] = ((const float4*)W)[(k + dk) * 32 + jg];
#pragma unroll
        for (int r = 0; r < 8; ++r) {
            float4 xv = *(const float4*)&xs[ng * 8 + r][k];
            acc[r].x = fmaf(xv.x, wr[0].x, acc[r].x);
            acc[r].y = fmaf(xv.x, wr[0].y, acc[r].y);
            acc[r].z = fmaf(xv.x, wr[0].z, acc[r].z);
            acc[r].w = fmaf(xv.x, wr[0].w, acc[r].w);
            acc[r].x = fmaf(xv.y, wr[1].x, acc[r].x);
            acc[r].y = fmaf(xv.y, wr[1].y, acc[r].y);
            acc[r].z = fmaf(xv.y, wr[1].z, acc[r].z);
            acc[r].w = fmaf(xv.y, wr[1].w, acc[r].w);
            acc[r].x = fmaf(xv.z, wr[2].x, acc[r].x);
            acc[r].y = fmaf(xv.z, wr[2].y, acc[r].y);
            acc[r].z = fmaf(xv.z, wr[2].z, acc[r].z);
            acc[r].w = fmaf(xv.z, wr[2].w, acc[r].w);
            acc[r].x = fmaf(xv.w, wr[3].x, acc[r].x);
            acc[r].y = fmaf(xv.w, wr[3].y, acc[r].y);
            acc[r].z = fmaf(xv.w, wr[3].z, acc[r].z);
            acc[r].w = fmaf(xv.w, wr[3].w, acc[r].w);
        }
    }
    float4 asv = ((const float4*)a_src)[jg];
    float4 adv = ((const float4*)a_dst)[jg];
#pragma unroll
    for (int r = 0; r < 8; ++r) {
        int n = n0 + ng * 8 + r;
        float ps = acc[r].x * asv.x + acc[r].y * asv.y + acc[r].z * asv.z + acc[r].w * asv.w;
        float pd = acc[r].x * adv.x + acc[r].y * adv.y + acc[r].z * adv.z + acc[r].w * adv.w;
        ps += __shfl_xor(ps, 1); pd += __shfl_xor(pd, 1);
        ps += __shfl_xor(ps, 2); pd += __shfl_xor(pd, 2);
        ps += __shfl_xor(ps, 4); pd += __shfl_xor(pd, 4);
        if (n < NN) {
            ((uint2*)xwb)[(size_t)n * 32 + jg] =
                make_uint2(packbf2(acc[r].x, acc[r].y), packbf2(acc[r].z, acc[r].w));
            if ((jg & 7) == 0) {
                int h = jg >> 3;
                as_[n * HH + h] = ps;
                ad_[n * HH + h] = pd;
            }
        }
    }
}

// ---------------- fused segment softmax + aggregate + bias + ELU ----------------
#define SWSTR 66
__global__ __launch_bounds__(256) void aggregate(
    const int* __restrict__ esrc, const int* __restrict__ row_start,
    const float* __restrict__ as_, const float* __restrict__ ad_,
    const unsigned* __restrict__ xwb, const float* __restrict__ bias,
    float* __restrict__ out) {
    __shared__ float2 sw_all[4][4 * SWSTR];
    int wid = (int)(threadIdx.x >> 6);
    int node = blockIdx.x * 4 + wid;
    if (node >= NN) return;
    int lane = threadIdx.x & 63;
    float2* sw = &sw_all[wid][0];
    int beg = row_start[node];
    int end = row_start[node + 1];
    float4 ad = ((const float4*)ad_)[node];

    int sub = lane >> 4;
    int c8 = lane & 15;
    int h = c8 >> 2;
    const char* xwp = (const char*)xwb + (c8 << 4);
    const char* asp = (const char*)as_;
    float4 accA = make_float4(0.f, 0.f, 0.f, 0.f);
    float4 accB = make_float4(0.f, 0.f, 0.f, 0.f);
    float dloc = 0.f;

    for (int base = beg; base < end; base += 64) {
        int i = base + lane;
        int cnt = end - base; if (cnt > 64) cnt = 64;
        if (i < end) {
            int s = esrc[i];
            float4 av = *(const float4*)(asp + ((unsigned)s << 4));
            float w0 = __expf(lrelu(av.x + ad.x));
            float w1 = __expf(lrelu(av.y + ad.y));
            float w2 = __expf(lrelu(av.z + ad.z));
            float w3 = __expf(lrelu(av.w + ad.w));
            float sf = __int_as_float(s);
            sw[0 * SWSTR + lane] = make_float2(sf, w0);
            sw[1 * SWSTR + lane] = make_float2(sf, w1);
            sw[2 * SWSTR + lane] = make_float2(sf, w2);
            sw[3 * SWSTR + lane] = make_float2(sf, w3);
        }
        int iters = (cnt + 3) >> 2;
        bool ok = sub < cnt;
        float2 sv = sw[h * SWSTR + (ok ? sub : 0)];
        float wj = ok ? sv.y : 0.f;
        unsigned row = ok ? ((unsigned)__float_as_int(sv.x) << 8) : 0u;
        uint4 v = *(const uint4*)(xwp + row);
        for (int it = 1; it <= iters; ++it) {
            int j1 = (it << 2) + sub;
            bool ok1 = j1 < cnt;
            float2 sv1 = sw[h * SWSTR + (ok1 ? j1 : 0)];
            float w1 = ok1 ? sv1.y : 0.f;
            unsigned row1 = ok1 ? ((unsigned)__float_as_int(sv1.x) << 8) : 0u;
            uint4 v1 = *(const uint4*)(xwp + row1);
            dloc += wj;
            accA.x = fmaf(wj, __uint_as_float(v.x << 16), accA.x);
            accA.y = fmaf(wj, __uint_as_float(v.x & 0xffff0000u), accA.y);
            accA.z = fmaf(wj, __uint_as_float(v.y << 16), accA.z);
            accA.w = fmaf(wj, __uint_as_float(v.y & 0xffff0000u), accA.w);
            accB.x = fmaf(wj, __uint_as_float(v.z << 16), accB.x);
            accB.y = fmaf(wj, __uint_as_float(v.z & 0xffff0000u), accB.y);
            accB.z = fmaf(wj, __uint_as_float(v.w << 16), accB.z);
            accB.w = fmaf(wj, __uint_as_float(v.w & 0xffff0000u), accB.w);
            v = v1; wj = w1;
        }
    }
#pragma unroll
    for (int off = 16; off <= 32; off <<= 1) {
        accA.x += __shfl_xor(accA.x, off);
        accA.y += __shfl_xor(accA.y, off);
        accA.z += __shfl_xor(accA.z, off);
        accA.w += __shfl_xor(accA.w, off);
        accB.x += __shfl_xor(accB.x, off);
        accB.y += __shfl_xor(accB.y, off);
        accB.z += __shfl_xor(accB.z, off);
        accB.w += __shfl_xor(accB.w, off);
        dloc += __shfl_xor(dloc, off);
    }
    if (sub == 0) {
        float inv = 1.f / dloc;
        float4 bb0 = ((const float4*)bias)[c8 * 2];
        float4 bb1 = ((const float4*)bias)[c8 * 2 + 1];
        float4 oA, oB;
        oA.x = fmaf(accA.x, inv, bb0.x);
        oA.y = fmaf(accA.y, inv, bb0.y);
        oA.z = fmaf(accA.z, inv, bb0.z);
        oA.w = fmaf(accA.w, inv, bb0.w);
        oB.x = fmaf(accB.x, inv, bb1.x);
        oB.y = fmaf(accB.y, inv, bb1.y);
        oB.z = fmaf(accB.z, inv, bb1.z);
        oB.w = fmaf(accB.w, inv, bb1.w);
        oA.x = oA.x > 0.f ? oA.x : expm1f(oA.x);
        oA.y = oA.y > 0.f ? oA.y : expm1f(oA.y);
        oA.z = oA.z > 0.f ? oA.z : expm1f(oA.z);
        oA.w = oA.w > 0.f ? oA.w : expm1f(oA.w);
        oB.x = oB.x > 0.f ? oB.x : expm1f(oB.x);
        oB.y = oB.y > 0.f ? oB.y : expm1f(oB.y);
        oB.z = oB.z > 0.f ? oB.z : expm1f(oB.z);
        oB.w = oB.w > 0.f ? oB.w : expm1f(oB.w);
        ((float4*)out)[(size_t)node * 32 + c8 * 2] = oA;
        ((float4*)out)[(size_t)node * 32 + c8 * 2 + 1] = oB;
    }
}

// ---------------- pooling + head ----------------
__global__ __launch_bounds__(128) void pool(
    const float* __restrict__ h1, const int* __restrict__ batch,
    float* __restrict__ sums, float* __restrict__ cnts) {
    int j = threadIdx.x;
    int n0 = blockIdx.x * 64;
    int n1 = n0 + 64; if (n1 > NN) n1 = NN;
    if (n0 >= NN) return;
    int cur = batch[n0];
    float local = 0.f;
    int cnt = 0;
    for (int n = n0; n < n1; ++n) {
        int g = batch[n];
        if (g != cur) {
            atomicAdd(&sums[cur * HC + j], local);
            if (j == 0) atomicAdd(&cnts[cur], (float)cnt);
            local = 0.f; cnt = 0; cur = g;
        }
        local += h1[(size_t)n * HC + j];
        ++cnt;
    }
    atomicAdd(&sums[cur * HC + j], local);
    if (j == 0) atomicAdd(&cnts[cur], (float)cnt);
}

__global__ __launch_bounds__(128) void head_out(
    const float* __restrict__ sums, const float* __restrict__ cnts,
    const float* __restrict__ lin_w, const float* __restrict__ lin_b,
    float* __restrict__ out) {
    int g = blockIdx.x;
    int j = threadIdx.x;
    float c = cnts[g];
    c = c > 1.f ? c : 1.f;
    float v = sums[g * HC + j] / c * lin_w[j];
    __shared__ float red[HC];
    red[j] = v;
    __syncthreads();
    for (int off = 64; off > 0; off >>= 1) {
        if (j < off) red[j] += red[j + off];
        __syncthreads();
    }
    if (j == 0) out[g] = red[0] + lin_b[0];
}

extern "C" void kernel_launch(void* const* d_in, const int* in_sizes, int n_in,
                              void* d_out, int out_size, void* d_ws, size_t ws_size,
                              hipStream_t stream) {
    const float* x   = (const float*)d_in[0];
    const int*   ei  = (const int*)d_in[1];
    const int*   bat = (const int*)d_in[2];
    const float* W0  = (const float*)d_in[3];
    const float* as0 = (const float*)d_in[4];
    const float* ad0 = (const float*)d_in[5];
    const float* b0  = (const float*)d_in[6];
    const float* W1  = (const float*)d_in[7];
    const float* as1 = (const float*)d_in[8];
    const float* ad1 = (const float*)d_in[9];
    const float* b1  = (const float*)d_in[10];
    const float* lw  = (const float*)d_in[11];
    const float* lb  = (const float*)d_in[12];
    float* out = (float*)d_out;

    char* w = (char*)d_ws;
    unsigned* xwb = (unsigned*)w; w += (size_t)NN * HC * 2;   // 12.8 MB bf16
    float* h0  = (float*)w;  w += (size_t)NN * HC * 4;        // 25.6 MB
    float* as_ = (float*)w;  w += (size_t)NN * HH * 4;
    float* ad_ = (float*)w;  w += (size_t)NN * HH * 4;
    int* row_start = (int*)w; w += (size_t)(NN + 1) * 4;
    int* bcur      = (int*)w; w += (size_t)NBKT * 4;
    int* esrc      = (int*)w; w += (size_t)NEDGE * 4;         // 6.6 MB
    uint2* pairs   = (uint2*)w; w += (size_t)NBKT * BCAP * 8; // 19.7 MB
    float* sums = (float*)w; w += (size_t)GG * HC * 4;
    float* cnts = (float*)w; w += (size_t)GG * 4;

    const int ab = (NN + 3) / 4;

    // ---- binit, then merged {gemm L0 || bucketize} ----
    binit<<<1, 256, 0, stream>>>(bcur);
    g0bkt<<<GB + NB1, 256, 0, stream>>>(x, W0, as0, ad0, xwb, as_, ad_,
                                        ei, bcur, pairs);
    debucket<<<NBKT, 512, 0, stream>>>(pairs, bcur, row_start, esrc);

    // ---- layer 0 aggregate ----
    aggregate<<<ab, 256, 0, stream>>>(esrc, row_start, as_, ad_, xwb, b0, h0);

    // ---- layer 1 ----
    gemm_alpha<<<GB, 256, 0, stream>>>(h0, W1, as1, ad1, xwb, as_, ad_);
    aggregate<<<ab, 256, 0, stream>>>(esrc, row_start, as_, ad_, xwb, b1, h0);

    // ---- pool + head ----
    hipMemsetAsync(sums, 0, ((size_t)GG * HC + GG) * 4, stream);
    pool<<<(NN + 63) / 64, 128, 0, stream>>>(h0, bat, sums, cnts);
    head_out<<<GG, 128, 0, stream>>>(sums, cnts, lw, lb, out);
}

// Round 19
// 247.502 us; speedup vs baseline: 1.1717x; 1.0074x over previous
//
#include <hip/hip_runtime.h>
#include <hip/hip_bf16.h>

#define NN 50000
#define EE 1600000
#define NEDGE (EE + NN)   // with self loops
#define HH 4
#define HC 128
#define GG 64
#define GMT 64            // nodes per standalone gemm block
#define GMT2 32           // nodes per merged-gemm block
#define NBKT 196          // dst buckets of 256 nodes
#define BCAP 12544        // pairs capacity per bucket (mean 8163, +48 sigma)
#define BKE 2048          // edges per bucketize block
#define NB1 ((EE + BKE - 1) / BKE)          // 782
#define GB ((NN + GMT - 1) / GMT)           // 782

__device__ __forceinline__ float lrelu(float x) { return fmaxf(x, 0.2f * x); }

__device__ __forceinline__ unsigned packbf2(float a, float b) {
    unsigned ua = __float_as_uint(a);
    ua = (ua + 0x7fffu + ((ua >> 16) & 1u)) >> 16;
    unsigned ub = __float_as_uint(b);
    ub = (ub + 0x7fffu + ((ub >> 16) & 1u)) >> 16;
    return ua | (ub << 16);
}

__global__ __launch_bounds__(256) void binit(int* __restrict__ bcur) {
    int t = blockIdx.x * 256 + threadIdx.x;
    if (t < NBKT) bcur[t] = t * BCAP;
}

// ---------------- merged dispatch: 3-way split ----------------
// bid%3 in {0,1}: gemm half-tile (32 nodes); bid%3==2: bucketize.
// pairs packed 4B: (d<<16)|s  (both < 65536).
__global__ __launch_bounds__(256) void g0bkt(
    const float* __restrict__ X, const float* __restrict__ W,
    const float* __restrict__ a_src, const float* __restrict__ a_dst,
    unsigned* __restrict__ xwb, float* __restrict__ as_, float* __restrict__ ad_,
    const int* __restrict__ ei, int* __restrict__ bcur, unsigned* __restrict__ pairs) {
    __shared__ union U {
        float xs[GMT2][HC + 4];                       // 16.9 KB
        struct {
            int cnt[NBKT], off[NBKT], gbase[NBKT];    // 2.4 KB
            int wsum[4], woff[4];
            unsigned stage[BKE];                      // 8 KB
        } b;
    } u;
    int t = threadIdx.x;
    int id = (int)(blockIdx.x / 3);
    int type = (int)(blockIdx.x % 3);

    if (type < 2) {
        // ---------------- gemm branch (32-node half-tile) ----------------
        int n0 = (id * 2 + type) * GMT2;
        for (int i = t; i < GMT2 * (HC / 4); i += 256) {
            int r = i >> 5, c4 = i & 31;
            int n = n0 + r;
            float4 v = (n < NN) ? ((const float4*)X)[(size_t)n * 32 + c4]
                                : make_float4(0.f, 0.f, 0.f, 0.f);
            *(float4*)&u.xs[r][c4 * 4] = v;
        }
        __syncthreads();
        int jg = t & 31;
        int ng = t >> 5;      // 8 node groups x 4 nodes
        float4 acc[4] = {};
        for (int k = 0; k < HC; k += 4) {
            float4 wr[4];
#pragma unroll
            for (int dk = 0; dk < 4; ++dk) wr[dk] = ((const float4*)W)[(k + dk) * 32 + jg];
#pragma unroll
            for (int r = 0; r < 4; ++r) {
                float4 xv = *(const float4*)&u.xs[ng * 4 + r][k];
                acc[r].x = fmaf(xv.x, wr[0].x, acc[r].x);
                acc[r].y = fmaf(xv.x, wr[0].y, acc[r].y);
                acc[r].z = fmaf(xv.x, wr[0].z, acc[r].z);
                acc[r].w = fmaf(xv.x, wr[0].w, acc[r].w);
                acc[r].x = fmaf(xv.y, wr[1].x, acc[r].x);
                acc[r].y = fmaf(xv.y, wr[1].y, acc[r].y);
                acc[r].z = fmaf(xv.y, wr[1].z, acc[r].z);
                acc[r].w = fmaf(xv.y, wr[1].w, acc[r].w);
                acc[r].x = fmaf(xv.z, wr[2].x, acc[r].x);
                acc[r].y = fmaf(xv.z, wr[2].y, acc[r].y);
                acc[r].z = fmaf(xv.z, wr[2].z, acc[r].z);
                acc[r].w = fmaf(xv.z, wr[2].w, acc[r].w);
                acc[r].x = fmaf(xv.w, wr[3].x, acc[r].x);
                acc[r].y = fmaf(xv.w, wr[3].y, acc[r].y);
                acc[r].z = fmaf(xv.w, wr[3].z, acc[r].z);
                acc[r].w = fmaf(xv.w, wr[3].w, acc[r].w);
            }
        }
        float4 asv = ((const float4*)a_src)[jg];
        float4 adv = ((const float4*)a_dst)[jg];
#pragma unroll
        for (int r = 0; r < 4; ++r) {
            int n = n0 + ng * 4 + r;
            float ps = acc[r].x * asv.x + acc[r].y * asv.y + acc[r].z * asv.z + acc[r].w * asv.w;
            float pd = acc[r].x * adv.x + acc[r].y * adv.y + acc[r].z * adv.z + acc[r].w * adv.w;
            ps += __shfl_xor(ps, 1); pd += __shfl_xor(pd, 1);
            ps += __shfl_xor(ps, 2); pd += __shfl_xor(pd, 2);
            ps += __shfl_xor(ps, 4); pd += __shfl_xor(pd, 4);
            if (n < NN) {
                ((uint2*)xwb)[(size_t)n * 32 + jg] =
                    make_uint2(packbf2(acc[r].x, acc[r].y), packbf2(acc[r].z, acc[r].w));
                if ((jg & 7) == 0) {
                    int h = jg >> 3;
                    as_[n * HH + h] = ps;
                    ad_[n * HH + h] = pd;
                }
            }
        }
    } else {
        // ---------------- bucketize branch ----------------
        int e0 = id * BKE;
        int n = EE - e0; if (n > BKE) n = BKE;
        for (int i = t; i < NBKT; i += 256) u.b.cnt[i] = 0;
        __syncthreads();
        unsigned dv[8], sv[8];
        int rk[8];
#pragma unroll
        for (int k = 0; k < 8; ++k) {
            int i = t + k * 256;
            if (i < n) {
                dv[k] = (unsigned)ei[EE + e0 + i];
                sv[k] = (unsigned)ei[e0 + i];
                rk[k] = atomicAdd(&u.b.cnt[dv[k] >> 8], 1);
            }
        }
        __syncthreads();
        {
            int v = (t < NBKT) ? u.b.cnt[t] : 0;
            int lane = t & 63, wv = t >> 6;
            int x = v;
#pragma unroll
            for (int o = 1; o < 64; o <<= 1) { int y = __shfl_up(x, o); if (lane >= o) x += y; }
            if (lane == 63) u.b.wsum[wv] = x;
            __syncthreads();
            if (t == 0) { int r = 0; for (int k2 = 0; k2 < 4; ++k2) { u.b.woff[k2] = r; r += u.b.wsum[k2]; } }
            __syncthreads();
            if (t < NBKT) u.b.off[t] = x - v + u.b.woff[wv];
        }
        __syncthreads();
#pragma unroll
        for (int k = 0; k < 8; ++k) {
            int i = t + k * 256;
            if (i < n) u.b.stage[u.b.off[dv[k] >> 8] + rk[k]] = (dv[k] << 16) | sv[k];
        }
        __syncthreads();
        if (t < NBKT) { int c = u.b.cnt[t]; u.b.gbase[t] = c ? atomicAdd(&bcur[t], c) : 0; }
        __syncthreads();
        for (int i = t; i < n; i += 256) {
            unsigned pr = u.b.stage[i];
            int b = (int)(pr >> 24);   // d>>8 == (pr>>16)>>8
            pairs[(size_t)u.b.gbase[b] + (i - u.b.off[b])] = pr;
        }
    }
}

// ---------------- debucket (computes its own bucket base) ----------------
__global__ __launch_bounds__(512) void debucket(const unsigned* __restrict__ pairs,
                                                const int* __restrict__ bcur,
                                                int* __restrict__ row_start,
                                                int* __restrict__ esrc) {
    __shared__ int cnt[256], off[256], cur[256];
    __shared__ int wsum[4], woff[4];
    __shared__ int wred[8];
    __shared__ int stage[BCAP + 256];
    int b = blockIdx.x, t = threadIdx.x;
    int n0 = b * 256;
    int nnode = NN - n0; if (nnode > 256) nnode = 256;
    int pcnt = bcur[b] - b * BCAP;

    int base;
    {
        int v = 0;
        if (t < b) {
            int pc = bcur[t] - t * BCAP;
            int nd = (t < NBKT - 1) ? 256 : (NN - (NBKT - 1) * 256);
            v = pc + nd;
        }
        int lane = t & 63, wv = t >> 6;
#pragma unroll
        for (int o = 1; o < 64; o <<= 1) v += __shfl_xor(v, o);
        if (lane == 0) wred[wv] = v;
        __syncthreads();
        if (t == 0) { int s = 0; for (int k = 0; k < 8; ++k) s += wred[k]; wred[0] = s; }
        __syncthreads();
        base = wred[0];
    }
    __syncthreads();
    if (t < 256) cnt[t] = 0;
    __syncthreads();
    for (int i = t; i < pcnt; i += 512)
        atomicAdd(&cnt[(pairs[(size_t)b * BCAP + i] >> 16) & 255u], 1);
    __syncthreads();
    {
        int v = 0, x = 0;
        int lane = t & 63, wv = t >> 6;
        if (t < 256) {
            v = cnt[t] + (t < nnode ? 1 : 0);
            x = v;
#pragma unroll
            for (int o = 1; o < 64; o <<= 1) { int y = __shfl_up(x, o); if (lane >= o) x += y; }
            if (lane == 63) wsum[wv] = x;
        }
        __syncthreads();
        if (t == 0) { int r = 0; for (int k = 0; k < 4; ++k) { woff[k] = r; r += wsum[k]; } }
        __syncthreads();
        if (t < 256) off[t] = x - v + woff[wv];
    }
    __syncthreads();
    if (t < nnode) {
        int o = off[t];
        stage[o] = n0 + t;
        cur[t] = o + 1;
        row_start[n0 + t] = base + o;
    }
    __syncthreads();
    for (int i = t; i < pcnt; i += 512) {
        unsigned pr = pairs[(size_t)b * BCAP + i];
        int p = atomicAdd(&cur[(pr >> 16) & 255u], 1);
        stage[p] = (int)(pr & 0xFFFFu);
    }
    __syncthreads();
    int tot = pcnt + nnode;
    for (int i = t; i < tot; i += 512) esrc[base + i] = stage[i];
    if (b == NBKT - 1 && t == 0) row_start[NN] = NEDGE;
}

// ---------------- GEMM (X @ W) + per-head alpha dots (layer 1) ----------------
__global__ __launch_bounds__(256) void gemm_alpha(
    const float* __restrict__ X, const float* __restrict__ W,
    const float* __restrict__ a_src, const float* __restrict__ a_dst,
    unsigned* __restrict__ xwb, float* __restrict__ as_, float* __restrict__ ad_) {
    __shared__ float xs[GMT][HC + 4];
    int tid = threadIdx.x;
    int n0 = blockIdx.x * GMT;
    for (int i = tid; i < GMT * (HC / 4); i += 256) {
        int r = i >> 5, c4 = i & 31;
        int n = n0 + r;
        float4 v = (n < NN) ? ((const float4*)X)[(size_t)n * 32 + c4]
                            : make_float4(0.f, 0.f, 0.f, 0.f);
        *(float4*)&xs[r][c4 * 4] = v;
    }
    __syncthreads();

    int jg = tid & 31;
    int ng = tid >> 5;
    float4 acc[8] = {};
    for (int k = 0; k < HC; k += 4) {
        float4 wr[4];
#pragma unroll
        for (int dk = 0; dk < 4; ++dk) wr[dk] = ((const float4*)W)[(k + dk) * 32 + jg];
#pragma unroll
        for (int r = 0; r < 8; ++r) {
            float4 xv = *(const float4*)&xs[ng * 8 + r][k];
            acc[r].x = fmaf(xv.x, wr[0].x, acc[r].x);
            acc[r].y = fmaf(xv.x, wr[0].y, acc[r].y);
            acc[r].z = fmaf(xv.x, wr[0].z, acc[r].z);
            acc[r].w = fmaf(xv.x, wr[0].w, acc[r].w);
            acc[r].x = fmaf(xv.y, wr[1].x, acc[r].x);
            acc[r].y = fmaf(xv.y, wr[1].y, acc[r].y);
            acc[r].z = fmaf(xv.y, wr[1].z, acc[r].z);
            acc[r].w = fmaf(xv.y, wr[1].w, acc[r].w);
            acc[r].x = fmaf(xv.z, wr[2].x, acc[r].x);
            acc[r].y = fmaf(xv.z, wr[2].y, acc[r].y);
            acc[r].z = fmaf(xv.z, wr[2].z, acc[r].z);
            acc[r].w = fmaf(xv.z, wr[2].w, acc[r].w);
            acc[r].x = fmaf(xv.w, wr[3].x, acc[r].x);
            acc[r].y = fmaf(xv.w, wr[3].y, acc[r].y);
            acc[r].z = fmaf(xv.w, wr[3].z, acc[r].z);
            acc[r].w = fmaf(xv.w, wr[3].w, acc[r].w);
        }
    }
    float4 asv = ((const float4*)a_src)[jg];
    float4 adv = ((const float4*)a_dst)[jg];
#pragma unroll
    for (int r = 0; r < 8; ++r) {
        int n = n0 + ng * 8 + r;
        float ps = acc[r].x * asv.x + acc[r].y * asv.y + acc[r].z * asv.z + acc[r].w * asv.w;
        float pd = acc[r].x * adv.x + acc[r].y * adv.y + acc[r].z * adv.z + acc[r].w * adv.w;
        ps += __shfl_xor(ps, 1); pd += __shfl_xor(pd, 1);
        ps += __shfl_xor(ps, 2); pd += __shfl_xor(pd, 2);
        ps += __shfl_xor(ps, 4); pd += __shfl_xor(pd, 4);
        if (n < NN) {
            ((uint2*)xwb)[(size_t)n * 32 + jg] =
                make_uint2(packbf2(acc[r].x, acc[r].y), packbf2(acc[r].z, acc[r].w));
            if ((jg & 7) == 0) {
                int h = jg >> 3;
                as_[n * HH + h] = ps;
                ad_[n * HH + h] = pd;
            }
        }
    }
}

// ---------------- fused segment softmax + aggregate + bias + ELU ----------------
#define SWSTR 66
__global__ __launch_bounds__(256) void aggregate(
    const int* __restrict__ esrc, const int* __restrict__ row_start,
    const float* __restrict__ as_, const float* __restrict__ ad_,
    const unsigned* __restrict__ xwb, const float* __restrict__ bias,
    float* __restrict__ out) {
    __shared__ float2 sw_all[4][4 * SWSTR];
    int wid = (int)(threadIdx.x >> 6);
    int node = blockIdx.x * 4 + wid;
    if (node >= NN) return;
    int lane = threadIdx.x & 63;
    float2* sw = &sw_all[wid][0];
    int beg = row_start[node];
    int end = row_start[node + 1];
    float4 ad = ((const float4*)ad_)[node];

    int sub = lane >> 4;
    int c8 = lane & 15;
    int h = c8 >> 2;
    const char* xwp = (const char*)xwb + (c8 << 4);
    const char* asp = (const char*)as_;
    float4 accA = make_float4(0.f, 0.f, 0.f, 0.f);
    float4 accB = make_float4(0.f, 0.f, 0.f, 0.f);
    float dloc = 0.f;

    for (int base = beg; base < end; base += 64) {
        int i = base + lane;
        int cnt = end - base; if (cnt > 64) cnt = 64;
        if (i < end) {
            int s = esrc[i];
            float4 av = *(const float4*)(asp + ((unsigned)s << 4));
            float w0 = __expf(lrelu(av.x + ad.x));
            float w1 = __expf(lrelu(av.y + ad.y));
            float w2 = __expf(lrelu(av.z + ad.z));
            float w3 = __expf(lrelu(av.w + ad.w));
            float sf = __int_as_float(s);
            sw[0 * SWSTR + lane] = make_float2(sf, w0);
            sw[1 * SWSTR + lane] = make_float2(sf, w1);
            sw[2 * SWSTR + lane] = make_float2(sf, w2);
            sw[3 * SWSTR + lane] = make_float2(sf, w3);
        }
        int iters = (cnt + 3) >> 2;
        bool ok = sub < cnt;
        float2 sv = sw[h * SWSTR + (ok ? sub : 0)];
        float wj = ok ? sv.y : 0.f;
        unsigned row = ok ? ((unsigned)__float_as_int(sv.x) << 8) : 0u;
        uint4 v = *(const uint4*)(xwp + row);
        for (int it = 1; it <= iters; ++it) {
            int j1 = (it << 2) + sub;
            bool ok1 = j1 < cnt;
            float2 sv1 = sw[h * SWSTR + (ok1 ? j1 : 0)];
            float w1 = ok1 ? sv1.y : 0.f;
            unsigned row1 = ok1 ? ((unsigned)__float_as_int(sv1.x) << 8) : 0u;
            uint4 v1 = *(const uint4*)(xwp + row1);
            dloc += wj;
            accA.x = fmaf(wj, __uint_as_float(v.x << 16), accA.x);
            accA.y = fmaf(wj, __uint_as_float(v.x & 0xffff0000u), accA.y);
            accA.z = fmaf(wj, __uint_as_float(v.y << 16), accA.z);
            accA.w = fmaf(wj, __uint_as_float(v.y & 0xffff0000u), accA.w);
            accB.x = fmaf(wj, __uint_as_float(v.z << 16), accB.x);
            accB.y = fmaf(wj, __uint_as_float(v.z & 0xffff0000u), accB.y);
            accB.z = fmaf(wj, __uint_as_float(v.w << 16), accB.z);
            accB.w = fmaf(wj, __uint_as_float(v.w & 0xffff0000u), accB.w);
            v = v1; wj = w1;
        }
    }
#pragma unroll
    for (int off = 16; off <= 32; off <<= 1) {
        accA.x += __shfl_xor(accA.x, off);
        accA.y += __shfl_xor(accA.y, off);
        accA.z += __shfl_xor(accA.z, off);
        accA.w += __shfl_xor(accA.w, off);
        accB.x += __shfl_xor(accB.x, off);
        accB.y += __shfl_xor(accB.y, off);
        accB.z += __shfl_xor(accB.z, off);
        accB.w += __shfl_xor(accB.w, off);
        dloc += __shfl_xor(dloc, off);
    }
    if (sub == 0) {
        float inv = 1.f / dloc;
        float4 bb0 = ((const float4*)bias)[c8 * 2];
        float4 bb1 = ((const float4*)bias)[c8 * 2 + 1];
        float4 oA, oB;
        oA.x = fmaf(accA.x, inv, bb0.x);
        oA.y = fmaf(accA.y, inv, bb0.y);
        oA.z = fmaf(accA.z, inv, bb0.z);
        oA.w = fmaf(accA.w, inv, bb0.w);
        oB.x = fmaf(accB.x, inv, bb1.x);
        oB.y = fmaf(accB.y, inv, bb1.y);
        oB.z = fmaf(accB.z, inv, bb1.z);
        oB.w = fmaf(accB.w, inv, bb1.w);
        oA.x = oA.x > 0.f ? oA.x : expm1f(oA.x);
        oA.y = oA.y > 0.f ? oA.y : expm1f(oA.y);
        oA.z = oA.z > 0.f ? oA.z : expm1f(oA.z);
        oA.w = oA.w > 0.f ? oA.w : expm1f(oA.w);
        oB.x = oB.x > 0.f ? oB.x : expm1f(oB.x);
        oB.y = oB.y > 0.f ? oB.y : expm1f(oB.y);
        oB.z = oB.z > 0.f ? oB.z : expm1f(oB.z);
        oB.w = oB.w > 0.f ? oB.w : expm1f(oB.w);
        ((float4*)out)[(size_t)node * 32 + c8 * 2] = oA;
        ((float4*)out)[(size_t)node * 32 + c8 * 2 + 1] = oB;
    }
}

// ---------------- pooling + head ----------------
__global__ __launch_bounds__(128) void pool(
    const float* __restrict__ h1, const int* __restrict__ batch,
    float* __restrict__ sums, float* __restrict__ cnts) {
    int j = threadIdx.x;
    int n0 = blockIdx.x * 64;
    int n1 = n0 + 64; if (n1 > NN) n1 = NN;
    if (n0 >= NN) return;
    int cur = batch[n0];
    float local = 0.f;
    int cnt = 0;
    for (int n = n0; n < n1; ++n) {
        int g = batch[n];
        if (g != cur) {
            atomicAdd(&sums[cur * HC + j], local);
            if (j == 0) atomicAdd(&cnts[cur], (float)cnt);
            local = 0.f; cnt = 0; cur = g;
        }
        local += h1[(size_t)n * HC + j];
        ++cnt;
    }
    atomicAdd(&sums[cur * HC + j], local);
    if (j == 0) atomicAdd(&cnts[cur], (float)cnt);
}

__global__ __launch_bounds__(128) void head_out(
    const float* __restrict__ sums, const float* __restrict__ cnts,
    const float* __restrict__ lin_w, const float* __restrict__ lin_b,
    float* __restrict__ out) {
    int g = blockIdx.x;
    int j = threadIdx.x;
    float c = cnts[g];
    c = c > 1.f ? c : 1.f;
    float v = sums[g * HC + j] / c * lin_w[j];
    __shared__ float red[HC];
    red[j] = v;
    __syncthreads();
    for (int off = 64; off > 0; off >>= 1) {
        if (j < off) red[j] += red[j + off];
        __syncthreads();
    }
    if (j == 0) out[g] = red[0] + lin_b[0];
}

extern "C" void kernel_launch(void* const* d_in, const int* in_sizes, int n_in,
                              void* d_out, int out_size, void* d_ws, size_t ws_size,
                              hipStream_t stream) {
    const float* x   = (const float*)d_in[0];
    const int*   ei  = (const int*)d_in[1];
    const int*   bat = (const int*)d_in[2];
    const float* W0  = (const float*)d_in[3];
    const float* as0 = (const float*)d_in[4];
    const float* ad0 = (const float*)d_in[5];
    const float* b0  = (const float*)d_in[6];
    const float* W1  = (const float*)d_in[7];
    const float* as1 = (const float*)d_in[8];
    const float* ad1 = (const float*)d_in[9];
    const float* b1  = (const float*)d_in[10];
    const float* lw  = (const float*)d_in[11];
    const float* lb  = (const float*)d_in[12];
    float* out = (float*)d_out;

    char* w = (char*)d_ws;
    unsigned* xwb = (unsigned*)w; w += (size_t)NN * HC * 2;   // 12.8 MB bf16
    float* h0  = (float*)w;  w += (size_t)NN * HC * 4;        // 25.6 MB
    float* as_ = (float*)w;  w += (size_t)NN * HH * 4;
    float* ad_ = (float*)w;  w += (size_t)NN * HH * 4;
    int* row_start = (int*)w; w += (size_t)(NN + 1) * 4;
    int* bcur      = (int*)w; w += (size_t)NBKT * 4;
    int* esrc      = (int*)w; w += (size_t)NEDGE * 4;         // 6.6 MB
    unsigned* pairs = (unsigned*)w; w += (size_t)NBKT * BCAP * 4; // 9.8 MB
    float* sums = (float*)w; w += (size_t)GG * HC * 4;
    float* cnts = (float*)w; w += (size_t)GG * 4;

    const int ab = (NN + 3) / 4;

    // ---- binit, then merged {gemm L0 || bucketize} ----
    binit<<<1, 256, 0, stream>>>(bcur);
    g0bkt<<<NB1 * 3, 256, 0, stream>>>(x, W0, as0, ad0, xwb, as_, ad_,
                                       ei, bcur, pairs);
    debucket<<<NBKT, 512, 0, stream>>>(pairs, bcur, row_start, esrc);

    // ---- layer 0 aggregate ----
    aggregate<<<ab, 256, 0, stream>>>(esrc, row_start, as_, ad_, xwb, b0, h0);

    // ---- layer 1 ----
    gemm_alpha<<<GB, 256, 0, stream>>>(h0, W1, as1, ad1, xwb, as_, ad_);
    aggregate<<<ab, 256, 0, stream>>>(esrc, row_start, as_, ad_, xwb, b1, h0);

    // ---- pool + head ----
    hipMemsetAsync(sums, 0, ((size_t)GG * HC + GG) * 4, stream);
    pool<<<(NN + 63) / 64, 128, 0, stream>>>(h0, bat, sums, cnts);
    head_out<<<GG, 128, 0, stream>>>(sums, cnts, lw, lb, out);
}